// Round 10
// baseline (28860.071 us; speedup 1.0000x reference)
//
#include <hip/hip_runtime.h>

#define EMB 300
#define VU 50000
#define VQ 30000
#define NCOLS 64
#define COLLEN 6
#define NTURNS 6
#define INLEN 128
#define TSTEPS 63
#define VOUT 30064
#define MAXK 5
#define NWD 60           // decode WGs
#define NWT 720          // k_tab WGs
#define NWC 240          // k_ctxsc WGs
#define FPAD 32
#define SENTU 0x7FC00001u
#define NGRP 8
#define GQW (TSTEPS*960)
#define GSC (TSTEPS*1024)
#define GH  (TSTEPS*320)

__device__ __forceinline__ float sigf(float x){ return 1.0f/(1.0f+__expf(-x)); }
__device__ __forceinline__ float tanhf_(float x){ return 1.0f - 2.0f/(1.0f+__expf(2.0f*x)); }
__device__ __forceinline__ float wsum(float v){
#pragma unroll
  for (int o=32;o;o>>=1) v += __shfl_xor(v,o);
  return v;
}
__device__ __forceinline__ float wmax(float v){
#pragma unroll
  for (int o=32;o;o>>=1) v = fmaxf(v,__shfl_xor(v,o));
  return v;
}

// write-through (agent-scope) store / uncached load for intra-kernel cross-WG data
__device__ __forceinline__ void gstore(float* p, float v){
  __hip_atomic_store((int*)p, __float_as_int(v), __ATOMIC_RELAXED, __HIP_MEMORY_SCOPE_AGENT);
}
__device__ __forceinline__ float gload(const float* p){
  return __int_as_float(__hip_atomic_load((const int*)p, __ATOMIC_RELAXED, __HIP_MEMORY_SCOPE_AGENT));
}
__device__ __forceinline__ void gpub(float* p, float v){
  (void)__hip_atomic_exchange((int*)p, __float_as_int(v), __ATOMIC_RELAXED, __HIP_MEMORY_SCOPE_AGENT);
}

// fence-free flag barrier: drain own (write-through) stores, set flag, poll all flags
__device__ __forceinline__ void fbar(int* flags, int nw, int w, int P)
{
  asm volatile("s_waitcnt vmcnt(0)" ::: "memory");
  __syncthreads();
  if (threadIdx.x == 0)
    __hip_atomic_store(flags + w*FPAD, P, __ATOMIC_RELAXED, __HIP_MEMORY_SCOPE_AGENT);
  if (threadIdx.x < 64) {
    int ok;
    do {
      ok = 1;
      for (int idx = threadIdx.x; idx < nw; idx += 64)
        ok &= (__hip_atomic_load(flags + idx*FPAD, __ATOMIC_RELAXED, __HIP_MEMORY_SCOPE_AGENT) >= P);
      if (!__all(ok)) { ok = 0; __builtin_amdgcn_s_sleep(4); }
    } while (!ok);
  }
  __syncthreads();
}

// decode-only barrier pieces (R7 verbatim)
__device__ __forceinline__ void garrive(int* flags, int w, int P){
  asm volatile("s_waitcnt vmcnt(0)" ::: "memory");
  __syncthreads();
  if (threadIdx.x == 0)
    __hip_atomic_store(flags + w*FPAD, P, __ATOMIC_RELAXED, __HIP_MEMORY_SCOPE_AGENT);
}
__device__ __forceinline__ void gwait(const int* flags, int P){
  if (threadIdx.x < 64) {
    int v;
    do {
      v = (threadIdx.x < NWD) ? __hip_atomic_load(flags + threadIdx.x*FPAD, __ATOMIC_RELAXED, __HIP_MEMORY_SCOPE_AGENT) : P;
    } while (__any(v < P));
  }
  __syncthreads();
}

template<int MAXV>
__device__ __forceinline__ void pollfetch(const float* __restrict__ src, float* dstLDS,
                                          int n, int modstride, int tid)
{
  float v[MAXV]; bool val[MAXV]; int idx[MAXV];
#pragma unroll
  for (int k = 0; k < MAXV; ++k) {
    idx[k] = tid + 256*k;
    bool ib = idx[k] < n;
    if (modstride) {
      int m = idx[k];
      while (m >= modstride) m -= modstride;
      ib = ib && (m < 300);
    }
    val[k] = ib;
  }
  for (;;) {
    bool ok = true;
#pragma unroll
    for (int k = 0; k < MAXV; ++k)
      if (val[k]) { v[k] = gload(src + idx[k]); ok = ok && (__float_as_uint(v[k]) != SENTU); }
    if (__all(ok)) break;
    __builtin_amdgcn_s_sleep(1);
  }
#pragma unroll
  for (int k = 0; k < MAXV; ++k) if (val[k]) dstLDS[idx[k]] = v[k];
  __syncthreads();
}

// ---------------- transpose tile helper ----------------
__device__ __forceinline__ void tr_tile(const float* __restrict__ in, float* __restrict__ out,
                                        int R, int C, int bx, int by,
                                        float (*tile)[33], int tid)
{
  const int rb = by*32, cb = bx*32;
  const int tx = tid & 31, ty = (tid >> 5) & 7;
  for (int k = 0; k < 32; k += 8) {
    int r = rb + ty + k, c = cb + tx;
    if (r < R && c < C) tile[ty+k][tx] = in[(size_t)r*C + c];
  }
  __syncthreads();
  for (int k = 0; k < 32; k += 8) {
    int c = cb + ty + k, r = rb + tx;
    if (c < C && r < R) out[(size_t)c*R + r] = tile[tx][ty+k];
  }
  __syncthreads();
}

// ---------------- setup: all transposes + schema BiLSTM + flag init (1 dispatch) ------------
__global__ __launch_bounds__(256) void k_setup(
    const float* __restrict__ aWq, float* __restrict__ WqT,
    const float* __restrict__ eWhh, float* __restrict__ WhhT,
    const float* __restrict__ dWih0, float* __restrict__ Wih0T,
    const float* __restrict__ tW, float* __restrict__ tWT,
    const float* __restrict__ eWih, float* __restrict__ eWT,
    const float* __restrict__ temb, const int* __restrict__ stok,
    const float* __restrict__ eb, float* __restrict__ SE0,
    int* __restrict__ eflags, int* __restrict__ tflags,
    int* __restrict__ cflags, int* __restrict__ dflags)
{
  __shared__ float tile[32][33];
  __shared__ float hl[152], cl[152], zl[600], xsr[304];
  const int tid = threadIdx.x;
  const int NCH = 3554 + 128 + 1;
  for (int ch = blockIdx.x; ch < NCH; ch += 240) {
    __syncthreads();
    if (ch < 400) {
      int z = ch/100, r = ch - z*100;
      tr_tile(aWq + (size_t)z*90000, WqT + (size_t)z*90000, 300, 300, r%10, r/10, tile, tid);
    } else if (ch < 970) {
      int c2 = ch - 400; int z = c2/95, r = c2 - z*95;
      tr_tile(eWhh + (size_t)z*90000, WhhT + (size_t)z*90000, 600, 150, r%5, r/5, tile, tid);
    } else if (ch < 2414) {
      int c2 = ch - 970;
      tr_tile(dWih0, Wih0T, 1200, 1200, c2%38, c2/38, tile, tid);
    } else if (ch < 2794) {
      int c2 = ch - 2414;
      tr_tile(tW, tWT, 300, 1200, c2%38, c2/38, tile, tid);
    } else if (ch < 3554) {
      int c2 = ch - 2794; int z = c2/380, r = c2 - z*380;
      tr_tile(eWih + 360000 + (size_t)z*360000, eWT + (size_t)z*360000, 1200, 300, r%10, r/10, tile, tid);
    } else if (ch < 3682) {
      // schema column BiLSTM, one unit per (col,dir)
      const int unit = ch - 3554;
      const int col = unit >> 1, dir = unit & 1;
      if (tid < 152) { hl[tid]=0.f; cl[tid]=0.f; }
      __syncthreads();
      const float* Wi = eWih + (size_t)dir*180000;
      const float* Wh = eWhh + (size_t)dir*90000;
      const float* bd = eb + dir*600;
      for (int s = 0; s < COLLEN; ++s) {
        const int pos = dir ? (COLLEN-1-s) : s;
        const int tok = stok[col*COLLEN + pos];
        const float* x = temb + (size_t)tok*300;
        for (int c = tid; c < 300; c += 256) xsr[c] = x[c];
        __syncthreads();
        for (int g = tid; g < 600; g += 256) {
          float a = bd[g];
          const float* wi = Wi + (size_t)g*300;
          for (int c = 0; c < 300; ++c) a += xsr[c]*wi[c];
          const float* wh = Wh + (size_t)g*150;
          for (int j = 0; j < 150; ++j) a += hl[j]*wh[j];
          zl[g] = a;
        }
        __syncthreads();
        if (tid < 150) {
          float ii=zl[tid], ff=zl[150+tid], gg=zl[300+tid], oo=zl[450+tid];
          float cn = sigf(ff)*cl[tid] + sigf(ii)*tanhf_(gg);
          cl[tid]=cn; hl[tid]=sigf(oo)*tanhf_(cn);
        }
        __syncthreads();
      }
      if (tid < 150) SE0[(size_t)col*300 + dir*150 + tid] = hl[tid];
      __syncthreads();
    } else {
      for (int i = tid; i < 2*FPAD;   i += 256) eflags[i] = 0;
      for (int i = tid; i < NWT*FPAD; i += 256) tflags[i] = 0;
      for (int i = tid; i < NWC*FPAD; i += 256) cflags[i] = 0;
      for (int i = tid; i < NWD*FPAD; i += 256) dflags[i] = 0;
    }
  }
}

// ---------------- encoder: gemm1|rec1|bar|gemm2|rec2 fused, 2 WGs x 640 ----------------
__global__ __launch_bounds__(640) void k_enc(
    const float* __restrict__ utter, const float* __restrict__ SEi,
    const int* __restrict__ iseq,
    const float* __restrict__ eWT, const float* __restrict__ eb,
    const float* __restrict__ WhhT,
    float* __restrict__ Xg, float* __restrict__ ys1, float* __restrict__ ys2,
    float* __restrict__ fh, float* __restrict__ fc,
    int turn, int* __restrict__ eflags)
{
  const int dir = blockIdx.x, tid = threadIdx.x;
  __shared__ float xs[16][304];
  __shared__ __align__(16) float hl[2][152];

  for (int layer = 0; layer < 2; ++layer) {
    const float* WT = eWT + (size_t)layer*360000;
    const float* bL = eb + 1200 + layer*1200;
    // ---- G: Xg for own dir half ----
    for (int pt = 0; pt < 8; ++pt) {
      for (int i = tid; i < 4800; i += 640) {
        int t = i/300, c = i - t*300;
        int p = pt*16 + t;
        float v;
        if (layer == 0) {
          int tok = iseq[p];
          v = (tok < VU) ? utter[(size_t)tok*300 + c] : SEi[(size_t)(tok-VU)*300 + c];
        } else v = gload(ys1 + (size_t)p*300 + c);
        xs[t][c] = v;
      }
      __syncthreads();
      if (tid < 600) {
        int g = dir*600 + tid;
        float b = bL[g];
        float acc[16];
#pragma unroll
        for (int t = 0; t < 16; ++t) acc[t] = b;
        for (int c = 0; c < 300; ++c) {
          float wv = WT[(size_t)c*1200 + g];
#pragma unroll
          for (int t = 0; t < 16; ++t) acc[t] += wv * xs[t][c];
        }
#pragma unroll
        for (int t = 0; t < 16; ++t) Xg[(size_t)(pt*16+t)*1200 + g] = acc[t];
      }
      __syncthreads();
    }
    // ---- R: recurrence (gate-interleaved lanes) ----
    {
      const float* wtb = WhhT + (size_t)(2+2*layer)*90000 + (size_t)dir*90000;
      const int g = (tid & 3)*150 + (tid >> 2);
      const bool act = (tid < 600);
      float w_[150];
      if (act) {
#pragma unroll
        for (int j = 0; j < 150; ++j) w_[j] = wtb[(size_t)j*600 + g];
      }
      if (tid < 152) { hl[0][tid] = 0.f; hl[1][tid] = 0.f; }
      float cr = 0.f;
      __syncthreads();
      int par = 0;
      float xg = act ? Xg[(size_t)(dir ? INLEN-1 : 0)*1200 + dir*600 + g] : 0.f;
      float* ys_ = layer ? ys2 : ys1;
      for (int s = 0; s < INLEN; ++s) {
        const int pos = dir ? (INLEN-1-s) : s;
        const int nxt = dir ? (INLEN-2-s) : (s+1);
        float xg_nx = (s+1 < INLEN && act) ? Xg[(size_t)nxt*1200 + dir*600 + g] : 0.f;
        float acc = 0.f;
        if (act) {
          float aa[8];
#pragma unroll
          for (int q = 0; q < 8; ++q) aa[q] = 0.f;
          const float4* h4 = (const float4*)hl[par];
#pragma unroll
          for (int j4 = 0; j4 < 37; ++j4) {
            float4 h = h4[j4];
            aa[j4&7] += w_[4*j4]*h.x + w_[4*j4+1]*h.y + w_[4*j4+2]*h.z + w_[4*j4+3]*h.w;
          }
          acc = xg + ((aa[0]+aa[1])+(aa[2]+aa[3])) + ((aa[4]+aa[5])+(aa[6]+aa[7]))
                + w_[148]*hl[par][148] + w_[149]*hl[par][149];
        }
        float a1 = __shfl_xor(acc, 1);
        float a2 = __shfl_xor(acc, 2);
        float a3 = __shfl_xor(acc, 3);
        if (act && (tid & 3) == 0) {
          int d = tid >> 2;
          float cn = sigf(a1)*cr + sigf(acc)*tanhf_(a2);
          cr = cn;
          float hn = sigf(a3)*tanhf_(cn);
          hl[par^1][d] = hn;
          if (layer) ys_[(size_t)pos*300 + dir*150 + d] = hn;           // cross-dispatch
          else gstore(ys_ + (size_t)pos*300 + dir*150 + d, hn);         // cross-WG
        }
        __syncthreads();
        par ^= 1;
        xg = xg_nx;
      }
      if (layer == 1 && act && (tid & 3) == 0) {
        int d = tid >> 2;
        fh[dir*150 + d] = hl[par][d];
        fc[dir*150 + d] = cr;
      }
    }
    if (layer == 0) fbar(eflags, 2, dir, turn+1);
  }
}

// ---------------- key family helper ----------------
__device__ __forceinline__ const float* key_ptr(int j, int nin, const float* SE1,
                                                const float* XH, const float* OH, int* fam)
{
  if (j < 64) { *fam = 0; return SE1 + (size_t)j*300; }
  if (j < 64+nin) { *fam = 1; return XH + (size_t)(j-64)*300; }
  *fam = 2; return OH + (size_t)(j-64-nin)*300;
}

// ---------------- schema_upd+hist | bar | tables (720 WGs) ----------------
__global__ __launch_bounds__(256) void k_tab(
    const float* __restrict__ SEi, const float* __restrict__ ys2,
    const float* __restrict__ fh, const float* __restrict__ fc,
    float* __restrict__ SEo, float* __restrict__ HH, float* __restrict__ CH,
    float* __restrict__ XH, const float* __restrict__ OH,
    const float* __restrict__ aWk, const float* __restrict__ Wih0T,
    const float* __restrict__ b0, const float* __restrict__ tWT,
    const float* __restrict__ qemb, const int* __restrict__ gt,
    float* __restrict__ KW, float* __restrict__ G2K,
    float* __restrict__ Ew, float* __restrict__ G1KT,
    int nin, int nout, int turn, int* __restrict__ tflags)
{
  const int w = blockIdx.x, tid = threadIdx.x;
  const int ln = tid & 63, wv4 = tid >> 6;
  const int NK = 64 + nin + nout, NT32 = NK >> 5;
  __shared__ float A[32][301];
  __shared__ float sl[304], al[128], red2[4];

  // ---- Phase A: schema update + history append (WGs 0..63, one row each) ----
  if (w < 64) {
    const int row = w;
    for (int d = tid; d < 300; d += 256) sl[d] = SEi[(size_t)row*300 + d];
    __syncthreads();
    if (tid < 128) {
      float a = 0;
      const float* yr = ys2 + (size_t)tid*300;
      for (int d = 0; d < 300; ++d) a += sl[d]*yr[d];
      al[tid] = a;
    }
    __syncthreads();
    if (tid < 64) { float m = fmaxf(al[tid], al[tid+64]); m = wmax(m); if (tid==0) red2[0]=m; }
    __syncthreads();
    if (tid < 128) al[tid] = __expf(al[tid] - red2[0]);
    __syncthreads();
    if (tid < 64) { float s = al[tid] + al[tid+64]; s = wsum(s); if (tid==0) red2[1]=s; }
    __syncthreads();
    const float invz = 1.0f/red2[1];
    for (int d = tid; d < 300; d += 256) {
      float a = sl[d];
      for (int j = 0; j < 128; ++j) a += (al[j]*invz) * ys2[(size_t)j*300 + d];
      gstore(SEo + (size_t)row*300 + d, a);
    }
    if (turn < MAXK) {
      for (int i = row*600 + tid; i < row*600 + 600; i += 256)
        gstore(XH + (size_t)turn*INLEN*300 + i, ys2[i]);
      if (row == 0)
        for (int d = tid; d < 300; d += 256) {
          gstore(HH + turn*300 + d, fh[d]);
          gstore(CH + turn*300 + d, fc[d]);
        }
    }
  }
  fbar(tflags, NWT, w, turn+1);

  // ---- Phase B: tables (kw | g2k | ew | g1kT), gload-staged keys ----
  const int nch = 2*NT32 + 20 + NT32*19;
  for (int b = w; b < nch; b += NWT) {
    __syncthreads();
    if (b < 2*NT32) {
      const int j0 = (b < NT32 ? b : b - NT32) * 32;
      int fam; const float* base = key_ptr(j0, nin, SEo, XH, OH, &fam);
      for (int jj = wv4*8; jj < wv4*8+8; ++jj)
        for (int c = ln; c < 300; c += 64)
          A[jj][c] = gload(base + (size_t)jj*300 + c);
      __syncthreads();
      if (b < NT32) {
        const float* W = aWk + (size_t)(1+fam)*90000;
        for (int rep = 0; rep < 2; ++rep) {
          int c = tid + rep*256;
          if (c < 300) {
            float acc[32];
#pragma unroll
            for (int j = 0; j < 32; ++j) acc[j] = 0.f;
            for (int d = 0; d < 300; ++d) {
              float wvv = W[(size_t)d*300 + c];
#pragma unroll
              for (int j = 0; j < 32; ++j) acc[j] += A[j][d]*wvv;
            }
#pragma unroll
            for (int j = 0; j < 32; ++j) KW[(size_t)(j0+j)*300 + c] = acc[j];
          }
        }
      } else {
        const int cb = 300 + fam*300;
        for (int rep = 0; rep < 2; ++rep) {
          int r = tid + rep*256;
          if (r < 300) {
            float acc[32];
#pragma unroll
            for (int j = 0; j < 32; ++j) acc[j] = 0.f;
            for (int d = 0; d < 300; ++d) {
              float wvv = tWT[(size_t)(cb+d)*300 + r];
#pragma unroll
              for (int j = 0; j < 32; ++j) acc[j] += A[j][d]*wvv;
            }
#pragma unroll
            for (int j = 0; j < 32; ++j) G2K[(size_t)(j0+j)*300 + r] = acc[j];
          }
        }
      }
    } else if (b < 2*NT32 + 20) {
      const int idx = b - 2*NT32;
      const int gx = idx % 5, ty = idx / 5;
      const int g = gx*256 + tid;
      const int tb = ty*16;
      for (int i = tid; i < 16*300; i += 256) {
        int k = i / 300, c = i - k*300;
        int t = tb + k;
        int tok = (t < 63) ? gt[t] : 0;
        A[k][c] = (tok < VQ) ? qemb[(size_t)tok*300 + c]
                             : gload(SEo + (size_t)(tok-VQ)*300 + c);
      }
      __syncthreads();
      if (g < 1200) {
        float bb = b0[g];
        float acc[16];
#pragma unroll
        for (int k = 0; k < 16; ++k) acc[k] = bb;
        for (int c = 0; c < 300; ++c) {
          float wvv = Wih0T[(size_t)c*1200 + g];
#pragma unroll
          for (int k = 0; k < 16; ++k) acc[k] += wvv * A[k][c];
        }
#pragma unroll
        for (int k = 0; k < 16; ++k)
          if (tb + k < 63) Ew[(size_t)(tb+k)*1200 + g] = acc[k];
      }
    } else {
      const int idx = b - (2*NT32 + 20);
      const int j0 = (idx % NT32)*32, r0 = (idx / NT32)*64;
      int fam; const float* base = key_ptr(j0, nin, SEo, XH, OH, &fam);
      for (int jj = wv4*8; jj < wv4*8+8; ++jj)
        for (int c = ln; c < 300; c += 64)
          A[jj][c] = gload(base + (size_t)jj*300 + c);
      __syncthreads();
      const int r = r0 + (tid & 63);
      const int jg = (tid >> 6)*8;
      const int cb = 300 + fam*300;
      float acc[8] = {0,0,0,0,0,0,0,0};
      if (r < 1200) {
        for (int c = 0; c < 300; ++c) {
          float wvv = Wih0T[(size_t)(cb+c)*1200 + r];
#pragma unroll
          for (int i = 0; i < 8; ++i) acc[i] += A[jg+i][c] * wvv;
        }
#pragma unroll
        for (int i = 0; i < 8; ++i) G1KT[(size_t)r*NK + j0 + jg + i] = acc[i];
      }
    }
    __syncthreads();
  }
}

// ---------------- persistent decoder: R7 verbatim ----------------
__global__ __launch_bounds__(256, 1) void k_dec(
    const float* __restrict__ KW, const float* __restrict__ G1KT,
    const float* __restrict__ Ew, const float* __restrict__ WqT,
    const float* __restrict__ av, const float* __restrict__ Wq0,
    const float* __restrict__ Wk0,
    const float* __restrict__ Whh0, const float* __restrict__ Wih1,
    const float* __restrict__ Whh1, const float* __restrict__ b1,
    const float* __restrict__ fh, const float* __restrict__ fc,
    const float* __restrict__ HH, const float* __restrict__ CH,
    float* __restrict__ h0b, float* __restrict__ c0b,
    float* __restrict__ xQW, float* __restrict__ xSC,
    float* __restrict__ xH1, float* __restrict__ xH2,
    float* __restrict__ Alog, float* __restrict__ H2log,
    int nin, int nout, int turn, int* __restrict__ flags)
{
  const int NK = 64 + nin + nout;
  const int w = blockIdx.x, tid = threadIdx.x;
  const int wv = tid >> 6, ln = tid & 63;
  const int grp = w & (NGRP-1);
  __shared__ float g1kl[20][1024];
  __shared__ float kwl[18][320];
  __shared__ float qWlp[3][320];
  __shared__ float vllp[3][320];
  __shared__ float ewl[63][20];
  __shared__ float scl[1024];
  __shared__ float dhl[320], h1l[320];
  __shared__ float pre1[20], pre2[20], zl[20], c1l[5], c2l[5];
  __shared__ float redA[4], alscA[8];
  __shared__ float wr0[4], wr1[4], wr2[4], rm[3], rz[3];
  const float SENTF = __uint_as_float(SENTU);

  for (int i = w*256 + tid; i < NGRP*GQW; i += NWD*256) gstore(xQW + i, SENTF);
  for (int i = w*256 + tid; i < NGRP*GSC; i += NWD*256) gstore(xSC + i, SENTF);
  for (int i = w*256 + tid; i < NGRP*GH;  i += NWD*256) gstore(xH1 + i, SENTF);
  for (int i = w*256 + tid; i < NGRP*GH;  i += NWD*256) gstore(xH2 + i, SENTF);

  for (int i = tid; i < 20*1024; i += 256) {
    int o = i >> 10, j = i & 1023;
    int row = w*5 + (o % 5) + 300*(o / 5);
    g1kl[o][j] = (j < NK) ? G1KT[(size_t)row*NK + j] : 0.f;
  }
  for (int i = tid; i < 18*320; i += 256) {
    int jo = i / 320, c = i - jo*320;
    int j = w*18 + jo;
    kwl[jo][c] = (c < 300 && j < NK) ? KW[(size_t)j*300 + c] : 0.f;
  }
  for (int i = tid; i < 3*320; i += 256) {
    int f = i / 320, c = i - f*320;
    vllp[f][c] = (c < 300) ? av[300 + f*300 + c] : 0.f;
    qWlp[f][c] = 0.f;
  }
  for (int i = tid; i < 63*20; i += 256) {
    int t = i / 20, o = i - t*20;
    int row = w*5 + (o % 5) + 300*(o / 5);
    ewl[t][o] = Ew[(size_t)t*1200 + row];
  }
  if (tid < 20) { dhl[300+tid] = 0.f; h1l[300+tid] = 0.f; }

  float rwh0[5][5], rwh1[5][5], rwi1[5][5], rwq4[4][5], b1r[5];
#pragma unroll
  for (int r = 0; r < 5; ++r) {
    int row = w*5 + r + 300*wv;
    b1r[r] = b1[row];
#pragma unroll
    for (int k = 0; k < 5; ++k) {
      int d = ln + 64*k;
      rwh0[r][k] = (d < 300) ? Whh0[(size_t)row*300 + d] : 0.f;
      rwh1[r][k] = (d < 300) ? Whh1[(size_t)row*300 + d] : 0.f;
      rwi1[r][k] = (d < 300) ? Wih1[(size_t)row*300 + d] : 0.f;
    }
  }
#pragma unroll
  for (int r = 0; r < 4; ++r) {
    int o = r*4 + wv;
    int q = w*15 + ((o < 15) ? o : 0);
    int fam = q / 300, c = q - fam*300;
    const float* bp = WqT + ((size_t)(1+fam)*300 + c)*300;
#pragma unroll
    for (int k = 0; k < 5; ++k) {
      int d = ln + 64*k;
      rwq4[r][k] = (o < 15 && d < 300) ? bp[d] : 0.f;
    }
  }
  const int jlo = (w*18 < NK) ? w*18 : NK-1;
  const int jhi = (w*18+17 < NK) ? w*18+17 : NK-1;
  const int f0 = (jlo < 64) ? 0 : (jlo < 64+nin ? 1 : 2);
  const int f1 = (jhi < 64) ? 0 : (jhi < 64+nin ? 1 : 2);
  __syncthreads();

  if (w == 0) {
    if (turn == 0) {
      for (int d = tid; d < 300; d += 256) { gstore(h0b+d, fh[d]); gstore(c0b+d, fc[d]); }
    } else {
      const int nh = turn;
      for (int d = tid; d < 300; d += 256) dhl[d] = fh[d];
      __syncthreads();
      for (int rep = 0; rep < 2; ++rep) {
        const float* keys = rep ? CH : HH;
        for (int c = tid; c < 300; c += 256) {
          float a = 0;
          for (int d = 0; d < 300; ++d) a += dhl[d]*Wq0[(size_t)d*300 + c];
          h1l[c] = a;
        }
        __syncthreads();
        for (int k = 0; k < nh; ++k) {
          const float* Kr = keys + (size_t)k*300;
          float part = 0;
          for (int c = tid; c < 300; c += 256) {
            float kw = 0;
            for (int d = 0; d < 300; ++d) kw += Kr[d]*Wk0[(size_t)d*300 + c];
            part += av[c]*tanhf_(h1l[c] + kw);
          }
          part = wsum(part);
          if (ln == 0) redA[wv] = part;
          __syncthreads();
          if (tid == 0) alscA[k] = redA[0]+redA[1]+redA[2]+redA[3];
          __syncthreads();
        }
        if (tid == 0) {
          float m = -1e30f;
          for (int k = 0; k < nh; ++k) m = fmaxf(m, alscA[k]);
          float z = 0;
          for (int k = 0; k < nh; ++k) { alscA[k] = __expf(alscA[k]-m); z += alscA[k]; }
          for (int k = 0; k < nh; ++k) alscA[k] /= z;
        }
        __syncthreads();
        if (rep == 0) {
          for (int c = tid; c < 300; c += 256) {
            float a = dhl[c];
            for (int k = 0; k < nh; ++k) a += alscA[k]*keys[(size_t)k*300 + c];
            scl[c] = a; gstore(h0b+c, a);
          }
          __syncthreads();
          for (int d = tid; d < 300; d += 256) dhl[d] = fc[d];
          __syncthreads();
        } else {
          for (int c = tid; c < 300; c += 256) {
            float a = scl[c];
            for (int k = 0; k < nh; ++k) a += alscA[k]*keys[(size_t)k*300 + c];
            gstore(c0b+c, a);
          }
        }
      }
    }
  }
  garrive(flags, w, turn+1);
  gwait(flags, turn+1);

  for (int i = tid; i < 300; i += 256) { float v = gload(h0b+i); dhl[i] = v; h1l[i] = v; }
  if (tid < 5) { float v = gload(c0b + w*5 + tid); c1l[tid] = v; c2l[tid] = v; }
  __syncthreads();

  for (int t = 0; t < TSTEPS; ++t) {
    if (t) pollfetch<2>(xH2 + (size_t)grp*GH + (size_t)(t-1)*320, dhl, 300, 0, tid);
#pragma unroll
    for (int r = 0; r < 4; ++r) {
      float a = 0;
#pragma unroll
      for (int k = 0; k < 5; ++k) a += rwq4[r][k]*dhl[ln + 64*k];
      a = wsum(a);
      int o = r*4 + wv;
      if (ln < NGRP && o < 15) {
        int q = w*15 + o, fam = q/300, c = q - fam*300;
        gpub(xQW + (size_t)ln*GQW + (size_t)t*960 + fam*320 + c, a);
      }
    }
#pragma unroll
    for (int r = 0; r < 5; ++r) {
      float a1 = 0, a2 = 0;
#pragma unroll
      for (int k = 0; k < 5; ++k) {
        float hv = h1l[ln + 64*k], dv = dhl[ln + 64*k];
        a1 += rwh0[r][k]*hv; a2 += rwh1[r][k]*dv;
      }
      a1 = wsum(a1); a2 = wsum(a2);
      if (ln == 0) { pre1[wv*5+r] = a1; pre2[wv*5+r] = a2 + b1r[r]; }
    }

    pollfetch<3>(xQW + (size_t)grp*GQW + (size_t)t*960 + f0*320, &qWlp[f0][0], (f1-f0+1)*320, 320, tid);
#pragma unroll
    for (int r = 0; r < 5; ++r) {
      int jo = wv*5 + r;
      int j = w*18 + jo;
      bool va = (jo < 18) && (j < NK);
      int f = va ? ((j < 64) ? 0 : (j < 64+nin ? 1 : 2)) : 0;
      int jc = (jo < 18) ? jo : 0;
      float a = 0;
#pragma unroll
      for (int k = 0; k < 5; ++k) {
        int c = ln + 64*k;
        a += vllp[f][c] * tanhf_(qWlp[f][c] + kwl[jc][c]);
      }
      a = wsum(a);
      if (ln < NGRP && va) gpub(xSC + (size_t)ln*GSC + (size_t)t*1024 + j, a);
    }

    pollfetch<4>(xSC + (size_t)grp*GSC + (size_t)t*1024, scl, NK, 0, tid);
    {
      float m0=-1e30f, m1=-1e30f, m2=-1e30f;
      for (int j = tid; j < NK; j += 256) {
        float x = scl[j];
        if (j < 64) m0 = fmaxf(m0,x); else if (j < 64+nin) m1 = fmaxf(m1,x); else m2 = fmaxf(m2,x);
      }
      m0 = wmax(m0); m1 = wmax(m1); m2 = wmax(m2);
      if (ln==0){ wr0[wv]=m0; wr1[wv]=m1; wr2[wv]=m2; }
      __syncthreads();
      if (tid==0){
        rm[0]=fmaxf(fmaxf(wr0[0],wr0[1]),fmaxf(wr0[2],wr0[3]));
        rm[1]=fmaxf(fmaxf(wr1[0],wr1[1]),fmaxf(wr1[2],wr1[3]));
        rm[2]=fmaxf(fmaxf(wr2[0],wr2[1]),fmaxf(wr2[2],wr2[3]));
      }
      __syncthreads();
      float s0=0,s1=0,s2=0;
      for (int j = tid; j < NK; j += 256) {
        int f = (j<64)?0:(j<64+nin?1:2);
        float e = __expf(scl[j] - rm[f]);
        scl[j] = e;
        if (f==0) s0+=e; else if (f==1) s1+=e; else s2+=e;
      }
      s0=wsum(s0); s1=wsum(s1); s2=wsum(s2);
      if (ln==0){ wr0[wv]=s0; wr1[wv]=s1; wr2[wv]=s2; }
      __syncthreads();
      if (tid==0){
        rz[0]=wr0[0]+wr0[1]+wr0[2]+wr0[3];
        rz[1]=wr1[0]+wr1[1]+wr1[2]+wr1[3];
        rz[2]=wr2[0]+wr2[1]+wr2[2]+wr2[3];
      }
      __syncthreads();
    }
    const int KC = NK >> 6;
    const int c1e = 1 + (nin >> 6);
    float inv0 = 1.0f/rz[0], inv1 = 1.0f/rz[1];
    float inv2 = (KC > c1e) ? 1.0f/rz[2] : 0.f;
    {
#pragma unroll 1
      for (int r = 0; r < 5; ++r) {
        int o = wv*5 + r;
        float a0 = scl[ln]*g1kl[o][ln];
        float a1 = 0, a2 = 0;
        for (int k = 1; k < c1e; ++k) { int j = ln + 64*k; a1 += scl[j]*g1kl[o][j]; }
        for (int k = c1e; k < KC; ++k) { int j = ln + 64*k; a2 += scl[j]*g1kl[o][j]; }
        float a = a0*inv0 + a1*inv1 + a2*inv2;
        a = wsum(a);
        if (ln == 0) zl[o] = a + ewl[t][o] + pre1[o];
      }
    }
    __syncthreads();
    if (tid < 5) {
      float ii=zl[tid], ff=zl[5+tid], gg=zl[10+tid], oo=zl[15+tid];
      float cn = sigf(ff)*c1l[tid] + sigf(ii)*tanhf_(gg);
      c1l[tid] = cn;
      float h1v = sigf(oo)*tanhf_(cn);
#pragma unroll
      for (int g = 0; g < NGRP; ++g)
        gpub(xH1 + (size_t)g*GH + (size_t)t*320 + w*5 + tid, h1v);
    }
    if (tid < 18) {
      int j = w*18 + tid;
      if (j < NK) {
        int f = (j<64)?0:(j<64+nin?1:2);
        float iv = (f==0)?inv0:((f==1)?inv1:inv2);
        Alog[(size_t)t*1024 + j] = scl[j]*iv;
      }
    }

    pollfetch<2>(xH1 + (size_t)grp*GH + (size_t)t*320, h1l, 300, 0, tid);
#pragma unroll
    for (int r = 0; r < 5; ++r) {
      float a = 0;
#pragma unroll
      for (int k = 0; k < 5; ++k) a += rwi1[r][k]*h1l[ln + 64*k];
      a = wsum(a);
      if (ln == 0) zl[wv*5+r] = a + pre2[wv*5+r];
    }
    __syncthreads();
    if (tid < 5) {
      int d = w*5 + tid;
      float ii=zl[tid], ff=zl[5+tid], gg=zl[10+tid], oo=zl[15+tid];
      float cn = sigf(ff)*c2l[tid] + sigf(ii)*tanhf_(gg);
      c2l[tid] = cn;
      float hn = sigf(oo)*tanhf_(cn);
#pragma unroll
      for (int g = 0; g < NGRP; ++g)
        gpub(xH2 + (size_t)g*GH + (size_t)t*320 + d, hn);
      H2log[(size_t)t*300 + d] = hn;
    }
  }
}

// ---------------- ctxout | bar | score (240 WGs) ----------------
__global__ __launch_bounds__(256) void k_ctxsc(
    const float* __restrict__ H2, const float* __restrict__ Al,
    const float* __restrict__ G2K, const float* __restrict__ tWT,
    const float* __restrict__ colW,
    float* __restrict__ o63, float* __restrict__ t63,
    const float* __restrict__ sqlW, const float* __restrict__ sqlb,
    const float* __restrict__ SEo, float* __restrict__ Dout,
    int NK, int turn, int* __restrict__ cflags)
{
  const int w = blockIdx.x, tid = threadIdx.x;
  __shared__ __align__(16) float olT[300][68];
  __shared__ float ol[304], h2l[304], all[1024];

  // ---- Phase A: ctxout (WGs 0..62) ----
  if (w < 63) {
    const int t = w;
    for (int d = tid; d < 300; d += 256) h2l[d] = H2[(size_t)t*300 + d];
    for (int j = tid; j < NK; j += 256) all[j] = Al[(size_t)t*1024 + j];
    __syncthreads();
    for (int r = tid; r < 300; r += 256) {
      float a = 0;
      for (int d = 0; d < 300; ++d) a += h2l[d]*tWT[(size_t)d*300 + r];
      for (int j = 0; j < NK; ++j) a += all[j]*G2K[(size_t)j*300 + r];
      float v = tanhf_(a);
      ol[r] = v;
      gstore(o63 + (size_t)t*300 + r, v);
    }
    __syncthreads();
    for (int e = tid; e < 300; e += 256) {
      float a = 0;
      const float* wc = colW + (size_t)e*300;
      for (int d = 0; d < 300; ++d) a += ol[d]*wc[d];
      gstore(t63 + (size_t)t*300 + e, a);
    }
  }
  fbar(cflags, NWC, w, turn+1);

  // ---- Phase B: score (WGs 0..117) ----
  if (w < 118) {
    const int vb = w;
    const int v = vb*256 + tid;
    for (int i = tid; i < 63*300; i += 256) {
      int k = i / 300, d = i - k*300;
      olT[d][k] = gload(o63 + i);
    }
    for (int d = tid; d < 300; d += 256) olT[d][63] = 0.f;
    __syncthreads();
    if ((vb+1)*256 <= VQ) {
      const float4* w4 = (const float4*)(sqlW + (size_t)v*300);
      float acc[64];
#pragma unroll
      for (int k = 0; k < 64; ++k) acc[k] = 0.f;
      for (int d4 = 0; d4 < 75; ++d4) {
        float4 wq = w4[d4];
        float wa[4] = {wq.x, wq.y, wq.z, wq.w};
#pragma unroll
        for (int s = 0; s < 4; ++s) {
          float ws = wa[s];
          const float4* row = (const float4*)&olT[d4*4+s][0];
#pragma unroll
          for (int k4 = 0; k4 < 16; ++k4) {
            float4 ov = row[k4];
            acc[4*k4+0] += ws*ov.x; acc[4*k4+1] += ws*ov.y;
            acc[4*k4+2] += ws*ov.z; acc[4*k4+3] += ws*ov.w;
          }
        }
      }
      const float b = sqlb[v];
      for (int k = 0; k < 63; ++k) Dout[(size_t)k*VOUT + v] = acc[k] + b;
    } else {
      // mixed tail block: vocab sub-pass (olT staged), then schema sub-pass (t63 staged)
      if (v < VQ) {
        const float4* w4 = (const float4*)(sqlW + (size_t)v*300);
        float acc[64];
#pragma unroll
        for (int k = 0; k < 64; ++k) acc[k] = 0.f;
        for (int d4 = 0; d4 < 75; ++d4) {
          float4 wq = w4[d4];
          float wa[4] = {wq.x, wq.y, wq.z, wq.w};
#pragma unroll
          for (int s = 0; s < 4; ++s) {
            float ws = wa[s];
            const float4* row = (const float4*)&olT[d4*4+s][0];
#pragma unroll
            for (int k4 = 0; k4 < 16; ++k4) {
              float4 ov = row[k4];
              acc[4*k4+0] += ws*ov.x; acc[4*k4+1] += ws*ov.y;
              acc[4*k4+2] += ws*ov.z; acc[4*k4+3] += ws*ov.w;
            }
          }
        }
        const float b = sqlb[v];
        for (int k = 0; k < 63; ++k) Dout[(size_t)k*VOUT + v] = acc[k] + b;
      }
      __syncthreads();
      for (int i = tid; i < 63*300; i += 256) {
        int k = i / 300, d = i - k*300;
        olT[d][k] = gload(t63 + i);
      }
      __syncthreads();
      if (v >= VQ && v < VOUT) {
        const float* wrow = SEo + (size_t)(v - VQ)*300;
        float acc[64];
#pragma unroll
        for (int k = 0; k < 64; ++k) acc[k] = 0.f;
        for (int d = 0; d < 300; ++d) {
          float ws = wrow[d];
          const float4* row = (const float4*)&olT[d][0];
#pragma unroll
          for (int k4 = 0; k4 < 16; ++k4) {
            float4 ov = row[k4];
            acc[4*k4+0] += ws*ov.x; acc[4*k4+1] += ws*ov.y;
            acc[4*k4+2] += ws*ov.z; acc[4*k4+3] += ws*ov.w;
          }
        }
        for (int k = 0; k < 63; ++k) Dout[(size_t)k*VOUT + v] = acc[k];
      }
    }
  }
}

// ---------------- log-softmax + argmax + OH row write (R7 verbatim) ----------------
__global__ void k_lsm(float* __restrict__ rows, const float* __restrict__ qemb,
                      const float* __restrict__ SE1, float* __restrict__ OHt)
{
  const int t = blockIdx.x, tid = threadIdx.x, wv = tid>>6, ln = tid&63;
  float* row = rows + (size_t)t*VOUT;
  __shared__ float rv[4], rs[4];
  __shared__ int ri[4];
  float m = -1e30f; int mi = VOUT;
  for (int j = tid; j < VOUT; j += 256) {
    float x = row[j];
    if (x > m) { m = x; mi = j; }
  }
#pragma unroll
  for (int o = 32; o; o >>= 1) {
    float om = __shfl_xor(m, o); int oi = __shfl_xor(mi, o);
    if (om > m || (om == m && oi < mi)) { m = om; mi = oi; }
  }
  if (ln == 0) { rv[wv] = m; ri[wv] = mi; }
  __syncthreads();
  if (tid == 0) {
    for (int k = 1; k < 4; ++k)
      if (rv[k] > rv[0] || (rv[k] == rv[0] && ri[k] < ri[0])) { rv[0]=rv[k]; ri[0]=ri[k]; }
  }
  __syncthreads();
  const float M = rv[0];
  float s = 0;
  for (int j = tid; j < VOUT; j += 256) s += __expf(row[j] - M);
  s = wsum(s);
  if (ln == 0) rs[wv] = s;
  __syncthreads();
  const float L = M + logf(rs[0]+rs[1]+rs[2]+rs[3]);
  for (int j = tid; j < VOUT; j += 256) row[j] -= L;
  if (OHt) {
    int id = ri[0];
    const float* src = (id < VQ) ? qemb + (size_t)id*300 : SE1 + (size_t)(id-VQ)*300;
    for (int d = tid; d < 300; d += 256) {
      OHt[(size_t)(t+1)*300 + d] = src[d];
      if (t == 0) OHt[d] = qemb[d];
    }
  }
}

extern "C" void kernel_launch(void* const* d_in, const int* in_sizes, int n_in,
                              void* d_out, int out_size, void* d_ws, size_t ws_size,
                              hipStream_t stream)
{
  const float* utter = (const float*)d_in[0];
  const float* qemb  = (const float*)d_in[1];
  const float* temb  = (const float*)d_in[2];
  const float* eWih  = (const float*)d_in[3];
  const float* eWhh  = (const float*)d_in[4];
  const float* eb    = (const float*)d_in[5];
  const float* aWq   = (const float*)d_in[6];
  const float* aWk   = (const float*)d_in[7];
  const float* av    = (const float*)d_in[8];
  const float* dWih0 = (const float*)d_in[9];
  const float* dWhh0 = (const float*)d_in[10];
  const float* db0   = (const float*)d_in[11];
  const float* dWih1 = (const float*)d_in[12];
  const float* dWhh1 = (const float*)d_in[13];
  const float* db1   = (const float*)d_in[14];
  const float* tW    = (const float*)d_in[15];
  const float* sqlW  = (const float*)d_in[16];
  const float* sqlb  = (const float*)d_in[17];
  const float* colW  = (const float*)d_in[18];
  const int* stok    = (const int*)d_in[19];
  const int* iseq    = (const int*)d_in[20];
  const int* ogt     = (const int*)d_in[21];
  float* dout = (float*)d_out;

  float* base = (float*)d_ws;
  size_t off = 0;
  auto A = [&](size_t n)->float*{ float* r = base + off; off += (n + 63) & ~(size_t)63; return r; };
  float* SE    = A(7*64*300);
  float* XH    = A(5*128*300);
  float* OH    = A(5*64*300);
  float* HH    = A(5*300);
  float* CH    = A(5*300);
  float* ys1   = A(128*300);
  float* ys2   = A(128*300);
  float* Xg    = A(128*1200);
  float* fh    = A(320);
  float* fc    = A(320);
  float* h0b   = A(320);
  float* c0b   = A(320);
  float* xQW   = A(NGRP*GQW);
  float* xSC   = A(NGRP*GSC);
  float* xH1   = A(NGRP*GH);
  float* xH2   = A(NGRP*GH);
  float* KW    = A(1024*300);
  float* G1KT  = A(1200*1024);
  float* G2K   = A(1024*300);
  float* EwB   = A(63*1200);
  float* Alog  = A(63*1024);
  float* H2lg  = A(64*300);
  float* o63   = A(64*300);
  float* t63   = A(64*300);
  A(512);
  float* WqT   = A(4*300*300);
  float* WhhT  = A(6*150*600);
  float* Wih0T = A(1200*1200);
  float* tWT   = A(1200*300);
  float* eWT   = A(2*300*1200);
  int* eflags = (int*)A(2*FPAD);
  int* tflags = (int*)A(NWT*FPAD);
  int* cflags = (int*)A(NWC*FPAD);
  int* dflags = (int*)A(NWD*FPAD);
  (void)ws_size; (void)in_sizes; (void)n_in; (void)out_size;

  k_setup<<<240, 256, 0, stream>>>(aWq, WqT, eWhh, WhhT, dWih0, Wih0T, tW, tWT,
                                   eWih, eWT, temb, stok, eb, SE,
                                   eflags, tflags, cflags, dflags);

  for (int i = 0; i < NTURNS; ++i) {
    const int kin  = (i+1 < MAXK) ? (i+1) : MAXK;
    const int kout = (i < MAXK) ? i : MAXK;
    const int nin = kin*128, nout = kout*64;
    const int NK = 64 + nin + nout;
    float* SEi = SE + (size_t)i*19200;
    float* SEo = SE + (size_t)(i+1)*19200;

    k_enc<<<2, 640, 0, stream>>>(utter, SEi, iseq + i*INLEN, eWT, eb, WhhT,
                                 Xg, ys1, ys2, fh, fc, i, eflags);
    k_tab<<<NWT, 256, 0, stream>>>(SEi, ys2, fh, fc, SEo, HH, CH, XH, OH,
                                   aWk, Wih0T, db0, tWT, qemb, ogt + i*64,
                                   KW, G2K, EwB, G1KT, nin, nout, i, tflags);
    k_dec<<<NWD, 256, 0, stream>>>(KW, G1KT, EwB, WqT, av, aWq, aWk,
                                   dWhh0, dWih1, dWhh1, db1, fh, fc, HH, CH,
                                   h0b, c0b, xQW, xSC, xH1, xH2, Alog, H2lg,
                                   nin, nout, i, dflags);
    k_ctxsc<<<NWC, 256, 0, stream>>>(H2lg, Alog, G2K, tWT, colW, o63, t63,
                                     sqlW, sqlb, SEo, dout + (size_t)i*63*VOUT,
                                     NK, i, cflags);
    k_lsm<<<63, 256, 0, stream>>>(dout + (size_t)i*63*VOUT, qemb, SEo,
                                  (i < MAXK) ? OH + (size_t)i*19200 : nullptr);
  }
}

// Round 11
// 19742.780 us; speedup vs baseline: 1.4618x; 1.4618x over previous
//
#include <hip/hip_runtime.h>

#define EMB 300
#define VU 50000
#define VQ 30000
#define NCOLS 64
#define COLLEN 6
#define NTURNS 6
#define INLEN 128
#define TSTEPS 63
#define VOUT 30064
#define MAXK 5
#define NWD 60           // decode WGs
#define NWT 720          // k_tab WGs
#define NWC 240          // k_ctxsc WGs
#define FPAD 32
#define SENTU 0x7FC00001u
#define NGRP 8
#define GQW (TSTEPS*960)
#define GSC (TSTEPS*1024)
#define GH  (TSTEPS*320)

__device__ __forceinline__ float sigf(float x){ return 1.0f/(1.0f+__expf(-x)); }
__device__ __forceinline__ float tanhf_(float x){ return 1.0f - 2.0f/(1.0f+__expf(2.0f*x)); }
__device__ __forceinline__ float wsum(float v){
#pragma unroll
  for (int o=32;o;o>>=1) v += __shfl_xor(v,o);
  return v;
}
__device__ __forceinline__ float wmax(float v){
#pragma unroll
  for (int o=32;o;o>>=1) v = fmaxf(v,__shfl_xor(v,o));
  return v;
}

// write-through (agent-scope) store / uncached load for intra-kernel cross-WG data
__device__ __forceinline__ void gstore(float* p, float v){
  __hip_atomic_store((int*)p, __float_as_int(v), __ATOMIC_RELAXED, __HIP_MEMORY_SCOPE_AGENT);
}
__device__ __forceinline__ float gload(const float* p){
  return __int_as_float(__hip_atomic_load((const int*)p, __ATOMIC_RELAXED, __HIP_MEMORY_SCOPE_AGENT));
}
__device__ __forceinline__ void gpub(float* p, float v){
  (void)__hip_atomic_exchange((int*)p, __float_as_int(v), __ATOMIC_RELAXED, __HIP_MEMORY_SCOPE_AGENT);
}

// fence-free flag barrier: drain own (write-through) stores, set flag, poll all flags
__device__ __forceinline__ void fbar(int* flags, int nw, int w, int P)
{
  asm volatile("s_waitcnt vmcnt(0)" ::: "memory");
  __syncthreads();
  if (threadIdx.x == 0)
    __hip_atomic_store(flags + w*FPAD, P, __ATOMIC_RELAXED, __HIP_MEMORY_SCOPE_AGENT);
  if (threadIdx.x < 64) {
    int ok;
    do {
      ok = 1;
      for (int idx = threadIdx.x; idx < nw; idx += 64)
        ok &= (__hip_atomic_load(flags + idx*FPAD, __ATOMIC_RELAXED, __HIP_MEMORY_SCOPE_AGENT) >= P);
      if (!__all(ok)) { ok = 0; __builtin_amdgcn_s_sleep(4); }
    } while (!ok);
  }
  __syncthreads();
}

// decode-only barrier pieces
__device__ __forceinline__ void garrive(int* flags, int w, int P){
  asm volatile("s_waitcnt vmcnt(0)" ::: "memory");
  __syncthreads();
  if (threadIdx.x == 0)
    __hip_atomic_store(flags + w*FPAD, P, __ATOMIC_RELAXED, __HIP_MEMORY_SCOPE_AGENT);
}
__device__ __forceinline__ void gwait(const int* flags, int P){
  if (threadIdx.x < 64) {
    int v;
    do {
      v = (threadIdx.x < NWD) ? __hip_atomic_load(flags + threadIdx.x*FPAD, __ATOMIC_RELAXED, __HIP_MEMORY_SCOPE_AGENT) : P;
    } while (__any(v < P));
  }
  __syncthreads();
}

template<int MAXV>
__device__ __forceinline__ void pollfetch(const float* __restrict__ src, float* dstLDS,
                                          int n, int modstride, int tid)
{
  float v[MAXV]; bool val[MAXV]; int idx[MAXV];
#pragma unroll
  for (int k = 0; k < MAXV; ++k) {
    idx[k] = tid + 256*k;
    bool ib = idx[k] < n;
    if (modstride) {
      int m = idx[k];
      while (m >= modstride) m -= modstride;
      ib = ib && (m < 300);
    }
    val[k] = ib;
  }
  for (;;) {
    bool ok = true;
#pragma unroll
    for (int k = 0; k < MAXV; ++k)
      if (val[k]) { v[k] = gload(src + idx[k]); ok = ok && (__float_as_uint(v[k]) != SENTU); }
    if (__all(ok)) break;
    __builtin_amdgcn_s_sleep(1);
  }
#pragma unroll
  for (int k = 0; k < MAXV; ++k) if (val[k]) dstLDS[idx[k]] = v[k];
  __syncthreads();
}

// ---------------- transpose tile helper ----------------
__device__ __forceinline__ void tr_tile(const float* __restrict__ in, float* __restrict__ out,
                                        int R, int C, int bx, int by,
                                        float (*tile)[33], int tid)
{
  const int rb = by*32, cb = bx*32;
  const int tx = tid & 31, ty = (tid >> 5) & 7;
  for (int k = 0; k < 32; k += 8) {
    int r = rb + ty + k, c = cb + tx;
    if (r < R && c < C) tile[ty+k][tx] = in[(size_t)r*C + c];
  }
  __syncthreads();
  for (int k = 0; k < 32; k += 8) {
    int c = cb + ty + k, r = rb + tx;
    if (c < C && r < R) out[(size_t)c*R + r] = tile[tx][ty+k];
  }
  __syncthreads();
}

// ---------------- setup: transposes + schema BiLSTM + flag init (1 dispatch) ----------------
__global__ __launch_bounds__(256) void k_setup(
    const float* __restrict__ aWq, float* __restrict__ WqT,
    const float* __restrict__ dWih0, float* __restrict__ Wih0T,
    const float* __restrict__ tW, float* __restrict__ tWT,
    const float* __restrict__ eWih, float* __restrict__ eWT,
    const float* __restrict__ eWhh,
    const float* __restrict__ temb, const int* __restrict__ stok,
    const float* __restrict__ eb, float* __restrict__ SE0,
    int* __restrict__ tflags, int* __restrict__ cflags, int* __restrict__ dflags)
{
  __shared__ float tile[32][33];
  __shared__ float hl[152], cl[152], zl[600], xsr[304];
  const int tid = threadIdx.x;
  const int NCH = 3113;
  for (int ch = blockIdx.x; ch < NCH; ch += 240) {
    __syncthreads();
    if (ch < 400) {
      int z = ch/100, r = ch - z*100;
      tr_tile(aWq + (size_t)z*90000, WqT + (size_t)z*90000, 300, 300, r%10, r/10, tile, tid);
    } else if (ch < 1844) {
      int c2 = ch - 400;
      tr_tile(dWih0, Wih0T, 1200, 1200, c2%38, c2/38, tile, tid);
    } else if (ch < 2224) {
      int c2 = ch - 1844;
      tr_tile(tW, tWT, 300, 1200, c2%38, c2/38, tile, tid);
    } else if (ch < 2984) {
      int c2 = ch - 2224; int z = c2/380, r = c2 - z*380;
      tr_tile(eWih + 360000 + (size_t)z*360000, eWT + (size_t)z*360000, 1200, 300, r%10, r/10, tile, tid);
    } else if (ch < 3112) {
      const int unit = ch - 2984;
      const int col = unit >> 1, dir = unit & 1;
      if (tid < 152) { hl[tid]=0.f; cl[tid]=0.f; }
      __syncthreads();
      const float* Wi = eWih + (size_t)dir*180000;
      const float* Wh = eWhh + (size_t)dir*90000;
      const float* bd = eb + dir*600;
      for (int s = 0; s < COLLEN; ++s) {
        const int pos = dir ? (COLLEN-1-s) : s;
        const int tok = stok[col*COLLEN + pos];
        const float* x = temb + (size_t)tok*300;
        for (int c = tid; c < 300; c += 256) xsr[c] = x[c];
        __syncthreads();
        for (int g = tid; g < 600; g += 256) {
          float a = bd[g];
          const float* wi = Wi + (size_t)g*300;
          for (int c = 0; c < 300; ++c) a += xsr[c]*wi[c];
          const float* wh = Wh + (size_t)g*150;
          for (int j = 0; j < 150; ++j) a += hl[j]*wh[j];
          zl[g] = a;
        }
        __syncthreads();
        if (tid < 150) {
          float ii=zl[tid], ff=zl[150+tid], gg=zl[300+tid], oo=zl[450+tid];
          float cn = sigf(ff)*cl[tid] + sigf(ii)*tanhf_(gg);
          cl[tid]=cn; hl[tid]=sigf(oo)*tanhf_(cn);
        }
        __syncthreads();
      }
      if (tid < 150) SE0[(size_t)col*300 + dir*150 + tid] = hl[tid];
      __syncthreads();
    } else {
      for (int i = tid; i < NWT*FPAD; i += 256) tflags[i] = 0;
      for (int i = tid; i < NWC*FPAD; i += 256) cflags[i] = 0;
      for (int i = tid; i < NWD*FPAD; i += 256) dflags[i] = 0;
    }
  }
}

// ---------------- Xg[pos][g] = embed/x[pos] @ WihT + b (40 WGs, LDS-staged rows) ------------
__global__ void k_gemm_xe(const float* __restrict__ src, const float* __restrict__ SEi,
                          const int* __restrict__ iseq, int mode,
                          const float* __restrict__ WihT, const float* __restrict__ bL,
                          float* __restrict__ Xg)
{
  __shared__ float xs[16][304];
  const int tid = threadIdx.x;
  const int p0 = blockIdx.y*16;
  for (int i = tid; i < 16*300; i += 256) {
    int t = i / 300, c = i - t*300;
    const float* xr;
    if (mode) xr = src + (size_t)(p0+t)*300;
    else {
      int tok = iseq[p0+t];
      xr = (tok < VU) ? src + (size_t)tok*300 : SEi + (size_t)(tok - VU)*300;
    }
    xs[t][c] = xr[c];
  }
  __syncthreads();
  const int g = blockIdx.x*256 + tid;
  if (g >= 1200) return;
  const float b = bL[g];
  float acc[16];
#pragma unroll
  for (int t = 0; t < 16; ++t) acc[t] = b;
  for (int c = 0; c < 300; ++c) {
    float wv = WihT[(size_t)c*1200 + g];
#pragma unroll
    for (int t = 0; t < 16; ++t) acc[t] += wv * xs[t][c];
  }
#pragma unroll
  for (int t = 0; t < 16; ++t) Xg[(size_t)(p0+t)*1200 + g] = acc[t];
}

// ---------------- BiLSTM recurrence; gate-interleaved lanes, contiguous weight preload ------
// lane L (<600) owns gate g=(L&3)*150+(L>>2); weights read DIRECT from eWhh (row-contiguous).
__global__ __launch_bounds__(640) void k_rec(
    const float* __restrict__ Xg, const float* __restrict__ WhhL,   // eWhh + (1+layer)*180000
    float* __restrict__ ys, float* __restrict__ fh, float* __restrict__ fc)
{
  const int dir = blockIdx.x, tid = threadIdx.x;
  __shared__ __align__(16) float hl[2][152];
  const int g = (tid & 3)*150 + (tid >> 2);
  const bool act = (tid < 600);
  float w_[150];
  if (act) {
    const float2* wr = (const float2*)(WhhL + (size_t)dir*90000 + (size_t)g*150);
#pragma unroll
    for (int m = 0; m < 75; ++m) { float2 v = wr[m]; w_[2*m] = v.x; w_[2*m+1] = v.y; }
  }
  if (tid < 152) { hl[0][tid] = 0.f; hl[1][tid] = 0.f; }
  float cr = 0.f;
  __syncthreads();
  int par = 0;
  float xg = act ? Xg[(size_t)(dir ? INLEN-1 : 0)*1200 + dir*600 + g] : 0.f;
  for (int s = 0; s < INLEN; ++s) {
    const int pos = dir ? (INLEN-1-s) : s;
    const int nxt = dir ? (INLEN-2-s) : (s+1);
    float xg_nx = (s+1 < INLEN && act) ? Xg[(size_t)nxt*1200 + dir*600 + g] : 0.f;
    float acc = 0.f;
    if (act) {
      float aa[8];
#pragma unroll
      for (int q = 0; q < 8; ++q) aa[q] = 0.f;
      const float4* h4 = (const float4*)hl[par];
#pragma unroll
      for (int j4 = 0; j4 < 37; ++j4) {
        float4 h = h4[j4];
        aa[j4&7] += w_[4*j4]*h.x + w_[4*j4+1]*h.y + w_[4*j4+2]*h.z + w_[4*j4+3]*h.w;
      }
      acc = xg + ((aa[0]+aa[1])+(aa[2]+aa[3])) + ((aa[4]+aa[5])+(aa[6]+aa[7]))
            + w_[148]*hl[par][148] + w_[149]*hl[par][149];
    }
    float a1 = __shfl_xor(acc, 1);
    float a2 = __shfl_xor(acc, 2);
    float a3 = __shfl_xor(acc, 3);
    if (act && (tid & 3) == 0) {
      int d = tid >> 2;
      float cn = sigf(a1)*cr + sigf(acc)*tanhf_(a2);
      cr = cn;
      float hn = sigf(a3)*tanhf_(cn);
      hl[par^1][d] = hn;
      ys[(size_t)pos*300 + dir*150 + d] = hn;
    }
    __syncthreads();
    par ^= 1;
    xg = xg_nx;
  }
  if (act && (tid & 3) == 0) {
    int d = tid >> 2;
    fh[dir*150 + d] = hl[par][d];
    fc[dir*150 + d] = cr;
  }
}

// ---------------- key family helper ----------------
__device__ __forceinline__ const float* key_ptr(int j, int nin, const float* SE1,
                                                const float* XH, const float* OH, int* fam)
{
  if (j < 64) { *fam = 0; return SE1 + (size_t)j*300; }
  if (j < 64+nin) { *fam = 1; return XH + (size_t)(j-64)*300; }
  *fam = 2; return OH + (size_t)(j-64-nin)*300;
}

// ---------------- schema_upd+hist | bar | tables (720 WGs) ----------------
__global__ __launch_bounds__(256) void k_tab(
    const float* __restrict__ SEi, const float* __restrict__ ys2,
    const float* __restrict__ fh, const float* __restrict__ fc,
    float* __restrict__ SEo, float* __restrict__ HH, float* __restrict__ CH,
    float* __restrict__ XH, const float* __restrict__ OH,
    const float* __restrict__ aWk, const float* __restrict__ Wih0T,
    const float* __restrict__ b0, const float* __restrict__ tWT,
    const float* __restrict__ qemb, const int* __restrict__ gt,
    float* __restrict__ KW, float* __restrict__ G2K,
    float* __restrict__ Ew, float* __restrict__ G1KT,
    int nin, int nout, int turn, int* __restrict__ tflags)
{
  const int w = blockIdx.x, tid = threadIdx.x;
  const int ln = tid & 63, wv4 = tid >> 6;
  const int NK = 64 + nin + nout, NT32 = NK >> 5;
  __shared__ float A[32][301];
  __shared__ float sl[304], al[128], red2[4];

  if (w < 64) {
    const int row = w;
    for (int d = tid; d < 300; d += 256) sl[d] = SEi[(size_t)row*300 + d];
    __syncthreads();
    if (tid < 128) {
      float a = 0;
      const float* yr = ys2 + (size_t)tid*300;
      for (int d = 0; d < 300; ++d) a += sl[d]*yr[d];
      al[tid] = a;
    }
    __syncthreads();
    if (tid < 64) { float m = fmaxf(al[tid], al[tid+64]); m = wmax(m); if (tid==0) red2[0]=m; }
    __syncthreads();
    if (tid < 128) al[tid] = __expf(al[tid] - red2[0]);
    __syncthreads();
    if (tid < 64) { float s = al[tid] + al[tid+64]; s = wsum(s); if (tid==0) red2[1]=s; }
    __syncthreads();
    const float invz = 1.0f/red2[1];
    for (int d = tid; d < 300; d += 256) {
      float a = sl[d];
      for (int j = 0; j < 128; ++j) a += (al[j]*invz) * ys2[(size_t)j*300 + d];
      gstore(SEo + (size_t)row*300 + d, a);
    }
    if (turn < MAXK) {
      for (int i = row*600 + tid; i < row*600 + 600; i += 256)
        gstore(XH + (size_t)turn*INLEN*300 + i, ys2[i]);
      if (row == 0)
        for (int d = tid; d < 300; d += 256) {
          gstore(HH + turn*300 + d, fh[d]);
          gstore(CH + turn*300 + d, fc[d]);
        }
    }
  }
  fbar(tflags, NWT, w, turn+1);

  const int nch = 2*NT32 + 20 + NT32*19;
  for (int b = w; b < nch; b += NWT) {
    __syncthreads();
    if (b < 2*NT32) {
      const int j0 = (b < NT32 ? b : b - NT32) * 32;
      int fam; const float* base = key_ptr(j0, nin, SEo, XH, OH, &fam);
      for (int jj = wv4*8; jj < wv4*8+8; ++jj)
        for (int c = ln; c < 300; c += 64)
          A[jj][c] = gload(base + (size_t)jj*300 + c);
      __syncthreads();
      if (b < NT32) {
        const float* W = aWk + (size_t)(1+fam)*90000;
        for (int rep = 0; rep < 2; ++rep) {
          int c = tid + rep*256;
          if (c < 300) {
            float acc[32];
#pragma unroll
            for (int j = 0; j < 32; ++j) acc[j] = 0.f;
            for (int d = 0; d < 300; ++d) {
              float wvv = W[(size_t)d*300 + c];
#pragma unroll
              for (int j = 0; j < 32; ++j) acc[j] += A[j][d]*wvv;
            }
#pragma unroll
            for (int j = 0; j < 32; ++j) KW[(size_t)(j0+j)*300 + c] = acc[j];
          }
        }
      } else {
        const int cb = 300 + fam*300;
        for (int rep = 0; rep < 2; ++rep) {
          int r = tid + rep*256;
          if (r < 300) {
            float acc[32];
#pragma unroll
            for (int j = 0; j < 32; ++j) acc[j] = 0.f;
            for (int d = 0; d < 300; ++d) {
              float wvv = tWT[(size_t)(cb+d)*300 + r];
#pragma unroll
              for (int j = 0; j < 32; ++j) acc[j] += A[j][d]*wvv;
            }
#pragma unroll
            for (int j = 0; j < 32; ++j) G2K[(size_t)(j0+j)*300 + r] = acc[j];
          }
        }
      }
    } else if (b < 2*NT32 + 20) {
      const int idx = b - 2*NT32;
      const int gx = idx % 5, ty = idx / 5;
      const int g = gx*256 + tid;
      const int tb = ty*16;
      for (int i = tid; i < 16*300; i += 256) {
        int k = i / 300, c = i - k*300;
        int t = tb + k;
        int tok = (t < 63) ? gt[t] : 0;
        A[k][c] = (tok < VQ) ? qemb[(size_t)tok*300 + c]
                             : gload(SEo + (size_t)(tok-VQ)*300 + c);
      }
      __syncthreads();
      if (g < 1200) {
        float bb = b0[g];
        float acc[16];
#pragma unroll
        for (int k = 0; k < 16; ++k) acc[k] = bb;
        for (int c = 0; c < 300; ++c) {
          float wvv = Wih0T[(size_t)c*1200 + g];
#pragma unroll
          for (int k = 0; k < 16; ++k) acc[k] += wvv * A[k][c];
        }
#pragma unroll
        for (int k = 0; k < 16; ++k)
          if (tb + k < 63) Ew[(size_t)(tb+k)*1200 + g] = acc[k];
      }
    } else {
      const int idx = b - (2*NT32 + 20);
      const int j0 = (idx % NT32)*32, r0 = (idx / NT32)*64;
      int fam; const float* base = key_ptr(j0, nin, SEo, XH, OH, &fam);
      for (int jj = wv4*8; jj < wv4*8+8; ++jj)
        for (int c = ln; c < 300; c += 64)
          A[jj][c] = gload(base + (size_t)jj*300 + c);
      __syncthreads();
      const int r = r0 + (tid & 63);
      const int jg = (tid >> 6)*8;
      const int cb = 300 + fam*300;
      float acc[8] = {0,0,0,0,0,0,0,0};
      if (r < 1200) {
        for (int c = 0; c < 300; ++c) {
          float wvv = Wih0T[(size_t)(cb+c)*1200 + r];
#pragma unroll
          for (int i = 0; i < 8; ++i) acc[i] += A[jg+i][c] * wvv;
        }
#pragma unroll
        for (int i = 0; i < 8; ++i) G1KT[(size_t)r*NK + j0 + jg + i] = acc[i];
      }
    }
    __syncthreads();
  }
}

// ---------------- persistent decoder ----------------
__global__ __launch_bounds__(256, 1) void k_dec(
    const float* __restrict__ KW, const float* __restrict__ G1KT,
    const float* __restrict__ Ew, const float* __restrict__ WqT,
    const float* __restrict__ av, const float* __restrict__ Wq0,
    const float* __restrict__ Wk0,
    const float* __restrict__ Whh0, const float* __restrict__ Wih1,
    const float* __restrict__ Whh1, const float* __restrict__ b1,
    const float* __restrict__ fh, const float* __restrict__ fc,
    const float* __restrict__ HH, const float* __restrict__ CH,
    float* __restrict__ h0b, float* __restrict__ c0b,
    float* __restrict__ xQW, float* __restrict__ xSC,
    float* __restrict__ xH1, float* __restrict__ xH2,
    float* __restrict__ Alog, float* __restrict__ H2log,
    int nin, int nout, int turn, int* __restrict__ flags)
{
  const int NK = 64 + nin + nout;
  const int w = blockIdx.x, tid = threadIdx.x;
  const int wv = tid >> 6, ln = tid & 63;
  const int grp = w & (NGRP-1);
  __shared__ float g1kl[20][1024];
  __shared__ float kwl[18][320];
  __shared__ float qWlp[3][320];
  __shared__ float vllp[3][320];
  __shared__ float ewl[63][20];
  __shared__ float scl[1024];
  __shared__ float dhl[320], h1l[320];
  __shared__ float pre1[20], pre2[20], zl[20], c1l[5], c2l[5];
  __shared__ float redA[4], alscA[8];
  __shared__ float wr0[4], wr1[4], wr2[4], rm[3], rz[3];
  const float SENTF = __uint_as_float(SENTU);

  for (int i = w*256 + tid; i < NGRP*GQW; i += NWD*256) gstore(xQW + i, SENTF);
  for (int i = w*256 + tid; i < NGRP*GSC; i += NWD*256) gstore(xSC + i, SENTF);
  for (int i = w*256 + tid; i < NGRP*GH;  i += NWD*256) gstore(xH1 + i, SENTF);
  for (int i = w*256 + tid; i < NGRP*GH;  i += NWD*256) gstore(xH2 + i, SENTF);

  for (int i = tid; i < 20*1024; i += 256) {
    int o = i >> 10, j = i & 1023;
    int row = w*5 + (o % 5) + 300*(o / 5);
    g1kl[o][j] = (j < NK) ? G1KT[(size_t)row*NK + j] : 0.f;
  }
  for (int i = tid; i < 18*320; i += 256) {
    int jo = i / 320, c = i - jo*320;
    int j = w*18 + jo;
    kwl[jo][c] = (c < 300 && j < NK) ? KW[(size_t)j*300 + c] : 0.f;
  }
  for (int i = tid; i < 3*320; i += 256) {
    int f = i / 320, c = i - f*320;
    vllp[f][c] = (c < 300) ? av[300 + f*300 + c] : 0.f;
    qWlp[f][c] = 0.f;
  }
  for (int i = tid; i < 63*20; i += 256) {
    int t = i / 20, o = i - t*20;
    int row = w*5 + (o % 5) + 300*(o / 5);
    ewl[t][o] = Ew[(size_t)t*1200 + row];
  }
  if (tid < 20) { dhl[300+tid] = 0.f; h1l[300+tid] = 0.f; }

  float rwh0[5][5], rwh1[5][5], rwi1[5][5], rwq4[4][5], b1r[5];
#pragma unroll
  for (int r = 0; r < 5; ++r) {
    int row = w*5 + r + 300*wv;
    b1r[r] = b1[row];
#pragma unroll
    for (int k = 0; k < 5; ++k) {
      int d = ln + 64*k;
      rwh0[r][k] = (d < 300) ? Whh0[(size_t)row*300 + d] : 0.f;
      rwh1[r][k] = (d < 300) ? Whh1[(size_t)row*300 + d] : 0.f;
      rwi1[r][k] = (d < 300) ? Wih1[(size_t)row*300 + d] : 0.f;
    }
  }
#pragma unroll
  for (int r = 0; r < 4; ++r) {
    int o = r*4 + wv;
    int q = w*15 + ((o < 15) ? o : 0);
    int fam = q / 300, c = q - fam*300;
    const float* bp = WqT + ((size_t)(1+fam)*300 + c)*300;
#pragma unroll
    for (int k = 0; k < 5; ++k) {
      int d = ln + 64*k;
      rwq4[r][k] = (o < 15 && d < 300) ? bp[d] : 0.f;
    }
  }
  const int jlo = (w*18 < NK) ? w*18 : NK-1;
  const int jhi = (w*18+17 < NK) ? w*18+17 : NK-1;
  const int f0 = (jlo < 64) ? 0 : (jlo < 64+nin ? 1 : 2);
  const int f1 = (jhi < 64) ? 0 : (jhi < 64+nin ? 1 : 2);
  __syncthreads();

  if (w == 0) {
    if (turn == 0) {
      for (int d = tid; d < 300; d += 256) { gstore(h0b+d, fh[d]); gstore(c0b+d, fc[d]); }
    } else {
      const int nh = turn;
      for (int d = tid; d < 300; d += 256) dhl[d] = fh[d];
      __syncthreads();
      for (int rep = 0; rep < 2; ++rep) {
        const float* keys = rep ? CH : HH;
        for (int c = tid; c < 300; c += 256) {
          float a = 0;
          for (int d = 0; d < 300; ++d) a += dhl[d]*Wq0[(size_t)d*300 + c];
          h1l[c] = a;
        }
        __syncthreads();
        for (int k = 0; k < nh; ++k) {
          const float* Kr = keys + (size_t)k*300;
          float part = 0;
          for (int c = tid; c < 300; c += 256) {
            float kw = 0;
            for (int d = 0; d < 300; ++d) kw += gload(Kr + d)*Wk0[(size_t)d*300 + c];
            part += av[c]*tanhf_(h1l[c] + kw);
          }
          part = wsum(part);
          if (ln == 0) redA[wv] = part;
          __syncthreads();
          if (tid == 0) alscA[k] = redA[0]+redA[1]+redA[2]+redA[3];
          __syncthreads();
        }
        if (tid == 0) {
          float m = -1e30f;
          for (int k = 0; k < nh; ++k) m = fmaxf(m, alscA[k]);
          float z = 0;
          for (int k = 0; k < nh; ++k) { alscA[k] = __expf(alscA[k]-m); z += alscA[k]; }
          for (int k = 0; k < nh; ++k) alscA[k] /= z;
        }
        __syncthreads();
        if (rep == 0) {
          for (int c = tid; c < 300; c += 256) {
            float a = dhl[c];
            for (int k = 0; k < nh; ++k) a += alscA[k]*gload(keys + (size_t)k*300 + c);
            scl[c] = a; gstore(h0b+c, a);
          }
          __syncthreads();
          for (int d = tid; d < 300; d += 256) dhl[d] = fc[d];
          __syncthreads();
        } else {
          for (int c = tid; c < 300; c += 256) {
            float a = scl[c];
            for (int k = 0; k < nh; ++k) a += alscA[k]*gload(keys + (size_t)k*300 + c);
            gstore(c0b+c, a);
          }
        }
      }
    }
  }
  garrive(flags, w, turn+1);
  gwait(flags, turn+1);

  for (int i = tid; i < 300; i += 256) { float v = gload(h0b+i); dhl[i] = v; h1l[i] = v; }
  if (tid < 5) { float v = gload(c0b + w*5 + tid); c1l[tid] = v; c2l[tid] = v; }
  __syncthreads();

  for (int t = 0; t < TSTEPS; ++t) {
    if (t) pollfetch<2>(xH2 + (size_t)grp*GH + (size_t)(t-1)*320, dhl, 300, 0, tid);
#pragma unroll
    for (int r = 0; r < 4; ++r) {
      float a = 0;
#pragma unroll
      for (int k = 0; k < 5; ++k) a += rwq4[r][k]*dhl[ln + 64*k];
      a = wsum(a);
      int o = r*4 + wv;
      if (ln < NGRP && o < 15) {
        int q = w*15 + o, fam = q/300, c = q - fam*300;
        gpub(xQW + (size_t)ln*GQW + (size_t)t*960 + fam*320 + c, a);
      }
    }
#pragma unroll
    for (int r = 0; r < 5; ++r) {
      float a1 = 0, a2 = 0;
#pragma unroll
      for (int k = 0; k < 5; ++k) {
        float hv = h1l[ln + 64*k], dv = dhl[ln + 64*k];
        a1 += rwh0[r][k]*hv; a2 += rwh1[r][k]*dv;
      }
      a1 = wsum(a1); a2 = wsum(a2);
      if (ln == 0) { pre1[wv*5+r] = a1; pre2[wv*5+r] = a2 + b1r[r]; }
    }

    pollfetch<3>(xQW + (size_t)grp*GQW + (size_t)t*960 + f0*320, &qWlp[f0][0], (f1-f0+1)*320, 320, tid);
#pragma unroll
    for (int r = 0; r < 5; ++r) {
      int jo = wv*5 + r;
      int j = w*18 + jo;
      bool va = (jo < 18) && (j < NK);
      int f = va ? ((j < 64) ? 0 : (j < 64+nin ? 1 : 2)) : 0;
      int jc = (jo < 18) ? jo : 0;
      float a = 0;
#pragma unroll
      for (int k = 0; k < 5; ++k) {
        int c = ln + 64*k;
        a += vllp[f][c] * tanhf_(qWlp[f][c] + kwl[jc][c]);
      }
      a = wsum(a);
      if (ln < NGRP && va) gpub(xSC + (size_t)ln*GSC + (size_t)t*1024 + j, a);
    }

    pollfetch<4>(xSC + (size_t)grp*GSC + (size_t)t*1024, scl, NK, 0, tid);
    {
      float m0=-1e30f, m1=-1e30f, m2=-1e30f;
      for (int j = tid; j < NK; j += 256) {
        float x = scl[j];
        if (j < 64) m0 = fmaxf(m0,x); else if (j < 64+nin) m1 = fmaxf(m1,x); else m2 = fmaxf(m2,x);
      }
      m0 = wmax(m0); m1 = wmax(m1); m2 = wmax(m2);
      if (ln==0){ wr0[wv]=m0; wr1[wv]=m1; wr2[wv]=m2; }
      __syncthreads();
      if (tid==0){
        rm[0]=fmaxf(fmaxf(wr0[0],wr0[1]),fmaxf(wr0[2],wr0[3]));
        rm[1]=fmaxf(fmaxf(wr1[0],wr1[1]),fmaxf(wr1[2],wr1[3]));
        rm[2]=fmaxf(fmaxf(wr2[0],wr2[1]),fmaxf(wr2[2],wr2[3]));
      }
      __syncthreads();
      float s0=0,s1=0,s2=0;
      for (int j = tid; j < NK; j += 256) {
        int f = (j<64)?0:(j<64+nin?1:2);
        float e = __expf(scl[j] - rm[f]);
        scl[j] = e;
        if (f==0) s0+=e; else if (f==1) s1+=e; else s2+=e;
      }
      s0=wsum(s0); s1=wsum(s1); s2=wsum(s2);
      if (ln==0){ wr0[wv]=s0; wr1[wv]=s1; wr2[wv]=s2; }
      __syncthreads();
      if (tid==0){
        rz[0]=wr0[0]+wr0[1]+wr0[2]+wr0[3];
        rz[1]=wr1[0]+wr1[1]+wr1[2]+wr1[3];
        rz[2]=wr2[0]+wr2[1]+wr2[2]+wr2[3];
      }
      __syncthreads();
    }
    const int KC = NK >> 6;
    const int c1e = 1 + (nin >> 6);
    float inv0 = 1.0f/rz[0], inv1 = 1.0f/rz[1];
    float inv2 = (KC > c1e) ? 1.0f/rz[2] : 0.f;
    {
#pragma unroll 1
      for (int r = 0; r < 5; ++r) {
        int o = wv*5 + r;
        float a0 = scl[ln]*g1kl[o][ln];
        float a1 = 0, a2 = 0;
        for (int k = 1; k < c1e; ++k) { int j = ln + 64*k; a1 += scl[j]*g1kl[o][j]; }
        for (int k = c1e; k < KC; ++k) { int j = ln + 64*k; a2 += scl[j]*g1kl[o][j]; }
        float a = a0*inv0 + a1*inv1 + a2*inv2;
        a = wsum(a);
        if (ln == 0) zl[o] = a + ewl[t][o] + pre1[o];
      }
    }
    __syncthreads();
    if (tid < 5) {
      float ii=zl[tid], ff=zl[5+tid], gg=zl[10+tid], oo=zl[15+tid];
      float cn = sigf(ff)*c1l[tid] + sigf(ii)*tanhf_(gg);
      c1l[tid] = cn;
      float h1v = sigf(oo)*tanhf_(cn);
#pragma unroll
      for (int g = 0; g < NGRP; ++g)
        gpub(xH1 + (size_t)g*GH + (size_t)t*320 + w*5 + tid, h1v);
    }
    if (tid < 18) {
      int j = w*18 + tid;
      if (j < NK) {
        int f = (j<64)?0:(j<64+nin?1:2);
        float iv = (f==0)?inv0:((f==1)?inv1:inv2);
        Alog[(size_t)t*1024 + j] = scl[j]*iv;
      }
    }

    pollfetch<2>(xH1 + (size_t)grp*GH + (size_t)t*320, h1l, 300, 0, tid);
#pragma unroll
    for (int r = 0; r < 5; ++r) {
      float a = 0;
#pragma unroll
      for (int k = 0; k < 5; ++k) a += rwi1[r][k]*h1l[ln + 64*k];
      a = wsum(a);
      if (ln == 0) zl[wv*5+r] = a + pre2[wv*5+r];
    }
    __syncthreads();
    if (tid < 5) {
      int d = w*5 + tid;
      float ii=zl[tid], ff=zl[5+tid], gg=zl[10+tid], oo=zl[15+tid];
      float cn = sigf(ff)*c2l[tid] + sigf(ii)*tanhf_(gg);
      c2l[tid] = cn;
      float hn = sigf(oo)*tanhf_(cn);
#pragma unroll
      for (int g = 0; g < NGRP; ++g)
        gpub(xH2 + (size_t)g*GH + (size_t)t*320 + d, hn);
      H2log[(size_t)t*300 + d] = hn;
    }
  }
}

// ---------------- ctxout | bar | score (240 WGs) ----------------
__global__ __launch_bounds__(256) void k_ctxsc(
    const float* __restrict__ H2, const float* __restrict__ Al,
    const float* __restrict__ G2K, const float* __restrict__ tWT,
    const float* __restrict__ colW,
    float* __restrict__ o63, float* __restrict__ t63,
    const float* __restrict__ sqlW, const float* __restrict__ sqlb,
    const float* __restrict__ SEo, float* __restrict__ Dout,
    int NK, int turn, int* __restrict__ cflags)
{
  const int w = blockIdx.x, tid = threadIdx.x;
  __shared__ __align__(16) float olT[300][68];
  __shared__ float ol[304], h2l[304], all[1024];

  if (w < 63) {
    const int t = w;
    for (int d = tid; d < 300; d += 256) h2l[d] = H2[(size_t)t*300 + d];
    for (int j = tid; j < NK; j += 256) all[j] = Al[(size_t)t*1024 + j];
    __syncthreads();
    for (int r = tid; r < 300; r += 256) {
      float a = 0;
      for (int d = 0; d < 300; ++d) a += h2l[d]*tWT[(size_t)d*300 + r];
      for (int j = 0; j < NK; ++j) a += all[j]*G2K[(size_t)j*300 + r];
      float v = tanhf_(a);
      ol[r] = v;
      gstore(o63 + (size_t)t*300 + r, v);
    }
    __syncthreads();
    for (int e = tid; e < 300; e += 256) {
      float a = 0;
      const float* wc = colW + (size_t)e*300;
      for (int d = 0; d < 300; ++d) a += ol[d]*wc[d];
      gstore(t63 + (size_t)t*300 + e, a);
    }
  }
  fbar(cflags, NWC, w, turn+1);

  if (w < 118) {
    const int vb = w;
    const int v = vb*256 + tid;
    for (int i = tid; i < 63*300; i += 256) {
      int k = i / 300, d = i - k*300;
      olT[d][k] = gload(o63 + i);
    }
    for (int d = tid; d < 300; d += 256) olT[d][63] = 0.f;
    __syncthreads();
    if ((vb+1)*256 <= VQ) {
      const float4* w4 = (const float4*)(sqlW + (size_t)v*300);
      float acc[64];
#pragma unroll
      for (int k = 0; k < 64; ++k) acc[k] = 0.f;
      for (int d4 = 0; d4 < 75; ++d4) {
        float4 wq = w4[d4];
        float wa[4] = {wq.x, wq.y, wq.z, wq.w};
#pragma unroll
        for (int s = 0; s < 4; ++s) {
          float ws = wa[s];
          const float4* row = (const float4*)&olT[d4*4+s][0];
#pragma unroll
          for (int k4 = 0; k4 < 16; ++k4) {
            float4 ov = row[k4];
            acc[4*k4+0] += ws*ov.x; acc[4*k4+1] += ws*ov.y;
            acc[4*k4+2] += ws*ov.z; acc[4*k4+3] += ws*ov.w;
          }
        }
      }
      const float b = sqlb[v];
      for (int k = 0; k < 63; ++k) Dout[(size_t)k*VOUT + v] = acc[k] + b;
    } else {
      if (v < VQ) {
        const float4* w4 = (const float4*)(sqlW + (size_t)v*300);
        float acc[64];
#pragma unroll
        for (int k = 0; k < 64; ++k) acc[k] = 0.f;
        for (int d4 = 0; d4 < 75; ++d4) {
          float4 wq = w4[d4];
          float wa[4] = {wq.x, wq.y, wq.z, wq.w};
#pragma unroll
          for (int s = 0; s < 4; ++s) {
            float ws = wa[s];
            const float4* row = (const float4*)&olT[d4*4+s][0];
#pragma unroll
            for (int k4 = 0; k4 < 16; ++k4) {
              float4 ov = row[k4];
              acc[4*k4+0] += ws*ov.x; acc[4*k4+1] += ws*ov.y;
              acc[4*k4+2] += ws*ov.z; acc[4*k4+3] += ws*ov.w;
            }
          }
        }
        const float b = sqlb[v];
        for (int k = 0; k < 63; ++k) Dout[(size_t)k*VOUT + v] = acc[k] + b;
      }
      __syncthreads();
      for (int i = tid; i < 63*300; i += 256) {
        int k = i / 300, d = i - k*300;
        olT[d][k] = gload(t63 + i);
      }
      __syncthreads();
      if (v >= VQ && v < VOUT) {
        const float* wrow = SEo + (size_t)(v - VQ)*300;
        float acc[64];
#pragma unroll
        for (int k = 0; k < 64; ++k) acc[k] = 0.f;
        for (int d = 0; d < 300; ++d) {
          float ws = gload(wrow + d);
          const float4* row = (const float4*)&olT[d][0];
#pragma unroll
          for (int k4 = 0; k4 < 16; ++k4) {
            float4 ov = row[k4];
            acc[4*k4+0] += ws*ov.x; acc[4*k4+1] += ws*ov.y;
            acc[4*k4+2] += ws*ov.z; acc[4*k4+3] += ws*ov.w;
          }
        }
        for (int k = 0; k < 63; ++k) Dout[(size_t)k*VOUT + v] = acc[k];
      }
    }
  }
}

// ---------------- log-softmax + argmax + OH row write ----------------
__global__ void k_lsm(float* __restrict__ rows, const float* __restrict__ qemb,
                      const float* __restrict__ SE1, float* __restrict__ OHt)
{
  const int t = blockIdx.x, tid = threadIdx.x, wv = tid>>6, ln = tid&63;
  float* row = rows + (size_t)t*VOUT;
  __shared__ float rv[4], rs[4];
  __shared__ int ri[4];
  float m = -1e30f; int mi = VOUT;
  for (int j = tid; j < VOUT; j += 256) {
    float x = row[j];
    if (x > m) { m = x; mi = j; }
  }
#pragma unroll
  for (int o = 32; o; o >>= 1) {
    float om = __shfl_xor(m, o); int oi = __shfl_xor(mi, o);
    if (om > m || (om == m && oi < mi)) { m = om; mi = oi; }
  }
  if (ln == 0) { rv[wv] = m; ri[wv] = mi; }
  __syncthreads();
  if (tid == 0) {
    for (int k = 1; k < 4; ++k)
      if (rv[k] > rv[0] || (rv[k] == rv[0] && ri[k] < ri[0])) { rv[0]=rv[k]; ri[0]=ri[k]; }
  }
  __syncthreads();
  const float M = rv[0];
  float s = 0;
  for (int j = tid; j < VOUT; j += 256) s += __expf(row[j] - M);
  s = wsum(s);
  if (ln == 0) rs[wv] = s;
  __syncthreads();
  const float L = M + logf(rs[0]+rs[1]+rs[2]+rs[3]);
  for (int j = tid; j < VOUT; j += 256) row[j] -= L;
  if (OHt) {
    int id = ri[0];
    const float* src = (id < VQ) ? qemb + (size_t)id*300 : SE1 + (size_t)(id-VQ)*300;
    for (int d = tid; d < 300; d += 256) {
      OHt[(size_t)(t+1)*300 + d] = src[d];
      if (t == 0) OHt[d] = qemb[d];
    }
  }
}

extern "C" void kernel_launch(void* const* d_in, const int* in_sizes, int n_in,
                              void* d_out, int out_size, void* d_ws, size_t ws_size,
                              hipStream_t stream)
{
  const float* utter = (const float*)d_in[0];
  const float* qemb  = (const float*)d_in[1];
  const float* temb  = (const float*)d_in[2];
  const float* eWih  = (const float*)d_in[3];
  const float* eWhh  = (const float*)d_in[4];
  const float* eb    = (const float*)d_in[5];
  const float* aWq   = (const float*)d_in[6];
  const float* aWk   = (const float*)d_in[7];
  const float* av    = (const float*)d_in[8];
  const float* dWih0 = (const float*)d_in[9];
  const float* dWhh0 = (const float*)d_in[10];
  const float* db0   = (const float*)d_in[11];
  const float* dWih1 = (const float*)d_in[12];
  const float* dWhh1 = (const float*)d_in[13];
  const float* db1   = (const float*)d_in[14];
  const float* tW    = (const float*)d_in[15];
  const float* sqlW  = (const float*)d_in[16];
  const float* sqlb  = (const float*)d_in[17];
  const float* colW  = (const float*)d_in[18];
  const int* stok    = (const int*)d_in[19];
  const int* iseq    = (const int*)d_in[20];
  const int* ogt     = (const int*)d_in[21];
  float* dout = (float*)d_out;

  float* base = (float*)d_ws;
  size_t off = 0;
  auto A = [&](size_t n)->float*{ float* r = base + off; off += (n + 63) & ~(size_t)63; return r; };
  float* SE    = A(7*64*300);
  float* XH    = A(5*128*300);
  float* OH    = A(5*64*300);
  float* HH    = A(5*300);
  float* CH    = A(5*300);
  float* ys1   = A(128*300);
  float* ys2   = A(128*300);
  float* Xg    = A(128*1200);
  float* fh    = A(320);
  float* fc    = A(320);
  float* fhs   = A(320);
  float* fcs   = A(320);
  float* h0b   = A(320);
  float* c0b   = A(320);
  float* xQW   = A(NGRP*GQW);
  float* xSC   = A(NGRP*GSC);
  float* xH1   = A(NGRP*GH);
  float* xH2   = A(NGRP*GH);
  float* KW    = A(1024*300);
  float* G1KT  = A(1200*1024);
  float* G2K   = A(1024*300);
  float* EwB   = A(63*1200);
  float* Alog  = A(63*1024);
  float* H2lg  = A(64*300);
  float* o63   = A(64*300);
  float* t63   = A(64*300);
  A(512);
  float* WqT   = A(4*300*300);
  float* Wih0T = A(1200*1200);
  float* tWT   = A(1200*300);
  float* eWT   = A(2*300*1200);
  int* tflags = (int*)A(NWT*FPAD);
  int* cflags = (int*)A(NWC*FPAD);
  int* dflags = (int*)A(NWD*FPAD);
  (void)ws_size; (void)in_sizes; (void)n_in; (void)out_size;

  k_setup<<<240, 256, 0, stream>>>(aWq, WqT, dWih0, Wih0T, tW, tWT, eWih, eWT, eWhh,
                                   temb, stok, eb, SE, tflags, cflags, dflags);

  for (int i = 0; i < NTURNS; ++i) {
    const int kin  = (i+1 < MAXK) ? (i+1) : MAXK;
    const int kout = (i < MAXK) ? i : MAXK;
    const int nin = kin*128, nout = kout*64;
    const int NK = 64 + nin + nout;
    float* SEi = SE + (size_t)i*19200;
    float* SEo = SE + (size_t)(i+1)*19200;

    k_gemm_xe<<<dim3(5,8), 256, 0, stream>>>(utter, SEi, iseq + i*INLEN, 0,
                                             eWT, eb + 1200, Xg);
    k_rec<<<2, 640, 0, stream>>>(Xg, eWhh + 180000, ys1, fhs, fcs);
    k_gemm_xe<<<dim3(5,8), 256, 0, stream>>>(ys1, SEi, iseq + i*INLEN, 1,
                                             eWT + 360000, eb + 2400, Xg);
    k_rec<<<2, 640, 0, stream>>>(Xg, eWhh + 360000, ys2, fh, fc);
    k_tab<<<NWT, 256, 0, stream>>>(SEi, ys2, fh, fc, SEo, HH, CH, XH, OH,
                                   aWk, Wih0T, db0, tWT, qemb, ogt + i*64,
                                   KW, G2K, EwB, G1KT, nin, nout, i, tflags);
    k_dec<<<NWD, 256, 0, stream>>>(KW, G1KT, EwB, WqT, av, aWq, aWk,
                                   dWhh0, dWih1, dWhh1, db1, fh, fc, HH, CH,
                                   h0b, c0b, xQW, xSC, xH1, xH2, Alog, H2lg,
                                   nin, nout, i, dflags);
    k_ctxsc<<<NWC, 256, 0, stream>>>(H2lg, Alog, G2K, tWT, colW, o63, t63,
                                     sqlW, sqlb, SEo, dout + (size_t)i*63*VOUT,
                                     NK, i, cflags);
    k_lsm<<<63, 256, 0, stream>>>(dout + (size_t)i*63*VOUT, qemb, SEo,
                                  (i < MAXK) ? OH + (size_t)i*19200 : nullptr);
  }
}

// Round 12
// 15166.347 us; speedup vs baseline: 1.9029x; 1.3017x over previous
//
#include <hip/hip_runtime.h>

#define EMB 300
#define VU 50000
#define VQ 30000
#define NCOLS 64
#define COLLEN 6
#define NTURNS 6
#define INLEN 128
#define TSTEPS 63
#define VOUT 30064
#define MAXK 5
#define NWD 60           // decode WGs
#define FPAD 32
#define SENTU 0x7FC00001u
#define NGRP 8
#define GQW (TSTEPS*960)
#define GSC (TSTEPS*1024)
#define GH  (TSTEPS*320)

__device__ __forceinline__ float sigf(float x){ return 1.0f/(1.0f+__expf(-x)); }
__device__ __forceinline__ float tanhf_(float x){ return 1.0f - 2.0f/(1.0f+__expf(2.0f*x)); }
__device__ __forceinline__ float wsum(float v){
#pragma unroll
  for (int o=32;o;o>>=1) v += __shfl_xor(v,o);
  return v;
}
__device__ __forceinline__ float wmax(float v){
#pragma unroll
  for (int o=32;o;o>>=1) v = fmaxf(v,__shfl_xor(v,o));
  return v;
}

// write-through (agent-scope) store / uncached load (decode mailboxes + small vectors)
__device__ __forceinline__ void gstore(float* p, float v){
  __hip_atomic_store((int*)p, __float_as_int(v), __ATOMIC_RELAXED, __HIP_MEMORY_SCOPE_AGENT);
}
__device__ __forceinline__ float gload(const float* p){
  return __int_as_float(__hip_atomic_load((const int*)p, __ATOMIC_RELAXED, __HIP_MEMORY_SCOPE_AGENT));
}
__device__ __forceinline__ void gpub(float* p, float v){
  (void)__hip_atomic_exchange((int*)p, __float_as_int(v), __ATOMIC_RELAXED, __HIP_MEMORY_SCOPE_AGENT);
}

// decode barrier pieces
__device__ __forceinline__ void garrive(int* flags, int w, int P){
  asm volatile("s_waitcnt vmcnt(0)" ::: "memory");
  __syncthreads();
  if (threadIdx.x == 0)
    __hip_atomic_store(flags + w*FPAD, P, __ATOMIC_RELAXED, __HIP_MEMORY_SCOPE_AGENT);
}
__device__ __forceinline__ void gwait(const int* flags, int P){
  if (threadIdx.x < 64) {
    int v;
    do {
      v = (threadIdx.x < NWD) ? __hip_atomic_load(flags + threadIdx.x*FPAD, __ATOMIC_RELAXED, __HIP_MEMORY_SCOPE_AGENT) : P;
    } while (__any(v < P));
  }
  __syncthreads();
}

template<int MAXV>
__device__ __forceinline__ void pollfetch(const float* __restrict__ src, float* dstLDS,
                                          int n, int modstride, int tid)
{
  float v[MAXV]; bool val[MAXV]; int idx[MAXV];
#pragma unroll
  for (int k = 0; k < MAXV; ++k) {
    idx[k] = tid + 256*k;
    bool ib = idx[k] < n;
    if (modstride) {
      int m = idx[k];
      while (m >= modstride) m -= modstride;
      ib = ib && (m < 300);
    }
    val[k] = ib;
  }
  for (;;) {
    bool ok = true;
#pragma unroll
    for (int k = 0; k < MAXV; ++k)
      if (val[k]) { v[k] = gload(src + idx[k]); ok = ok && (__float_as_uint(v[k]) != SENTU); }
    if (__all(ok)) break;
    __builtin_amdgcn_s_sleep(1);
  }
#pragma unroll
  for (int k = 0; k < MAXV; ++k) if (val[k]) dstLDS[idx[k]] = v[k];
  __syncthreads();
}

// ---------------- transpose tile helper ----------------
__device__ __forceinline__ void tr_tile(const float* __restrict__ in, float* __restrict__ out,
                                        int R, int C, int bx, int by,
                                        float (*tile)[33], int tid)
{
  const int rb = by*32, cb = bx*32;
  const int tx = tid & 31, ty = (tid >> 5) & 7;
  for (int k = 0; k < 32; k += 8) {
    int r = rb + ty + k, c = cb + tx;
    if (r < R && c < C) tile[ty+k][tx] = in[(size_t)r*C + c];
  }
  __syncthreads();
  for (int k = 0; k < 32; k += 8) {
    int c = cb + ty + k, r = rb + tx;
    if (c < C && r < R) out[(size_t)c*R + r] = tile[tx][ty+k];
  }
  __syncthreads();
}

// ---------------- setup: transposes + schema BiLSTM + flag init (1 dispatch) ----------------
__global__ __launch_bounds__(256) void k_setup(
    const float* __restrict__ aWq, float* __restrict__ WqT,
    const float* __restrict__ dWih0, float* __restrict__ Wih0T,
    const float* __restrict__ tW, float* __restrict__ tWT,
    const float* __restrict__ eWih, float* __restrict__ eWT,
    const float* __restrict__ eWhh,
    const float* __restrict__ temb, const int* __restrict__ stok,
    const float* __restrict__ eb, float* __restrict__ SE0,
    int* __restrict__ dflags)
{
  __shared__ float tile[32][33];
  __shared__ float hl[152], cl[152], zl[600], xsr[304];
  const int tid = threadIdx.x;
  const int NCH = 3113;
  for (int ch = blockIdx.x; ch < NCH; ch += 240) {
    __syncthreads();
    if (ch < 400) {
      int z = ch/100, r = ch - z*100;
      tr_tile(aWq + (size_t)z*90000, WqT + (size_t)z*90000, 300, 300, r%10, r/10, tile, tid);
    } else if (ch < 1844) {
      int c2 = ch - 400;
      tr_tile(dWih0, Wih0T, 1200, 1200, c2%38, c2/38, tile, tid);
    } else if (ch < 2224) {
      int c2 = ch - 1844;
      tr_tile(tW, tWT, 300, 1200, c2%38, c2/38, tile, tid);
    } else if (ch < 2984) {
      int c2 = ch - 2224; int z = c2/380, r = c2 - z*380;
      tr_tile(eWih + 360000 + (size_t)z*360000, eWT + (size_t)z*360000, 1200, 300, r%10, r/10, tile, tid);
    } else if (ch < 3112) {
      const int unit = ch - 2984;
      const int col = unit >> 1, dir = unit & 1;
      if (tid < 152) { hl[tid]=0.f; cl[tid]=0.f; }
      __syncthreads();
      const float* Wi = eWih + (size_t)dir*180000;
      const float* Wh = eWhh + (size_t)dir*90000;
      const float* bd = eb + dir*600;
      for (int s = 0; s < COLLEN; ++s) {
        const int pos = dir ? (COLLEN-1-s) : s;
        const int tok = stok[col*COLLEN + pos];
        const float* x = temb + (size_t)tok*300;
        for (int c = tid; c < 300; c += 256) xsr[c] = x[c];
        __syncthreads();
        for (int g = tid; g < 600; g += 256) {
          float a = bd[g];
          const float* wi = Wi + (size_t)g*300;
          for (int c = 0; c < 300; ++c) a += xsr[c]*wi[c];
          const float* wh = Wh + (size_t)g*150;
          for (int j = 0; j < 150; ++j) a += hl[j]*wh[j];
          zl[g] = a;
        }
        __syncthreads();
        if (tid < 150) {
          float ii=zl[tid], ff=zl[150+tid], gg=zl[300+tid], oo=zl[450+tid];
          float cn = sigf(ff)*cl[tid] + sigf(ii)*tanhf_(gg);
          cl[tid]=cn; hl[tid]=sigf(oo)*tanhf_(cn);
        }
        __syncthreads();
      }
      if (tid < 150) SE0[(size_t)col*300 + dir*150 + tid] = hl[tid];
      __syncthreads();
    } else {
      for (int i = tid; i < NWD*FPAD; i += 256) dflags[i] = 0;
    }
  }
}

// ---------------- Xg[pos][g] = embed/x[pos] @ WihT + b (40 WGs, LDS-staged rows) ------------
__global__ void k_gemm_xe(const float* __restrict__ src, const float* __restrict__ SEi,
                          const int* __restrict__ iseq, int mode,
                          const float* __restrict__ WihT, const float* __restrict__ bL,
                          float* __restrict__ Xg)
{
  __shared__ float xs[16][304];
  const int tid = threadIdx.x;
  const int p0 = blockIdx.y*16;
  for (int i = tid; i < 16*300; i += 256) {
    int t = i / 300, c = i - t*300;
    const float* xr;
    if (mode) xr = src + (size_t)(p0+t)*300;
    else {
      int tok = iseq[p0+t];
      xr = (tok < VU) ? src + (size_t)tok*300 : SEi + (size_t)(tok - VU)*300;
    }
    xs[t][c] = xr[c];
  }
  __syncthreads();
  const int g = blockIdx.x*256 + tid;
  if (g >= 1200) return;
  const float b = bL[g];
  float acc[16];
#pragma unroll
  for (int t = 0; t < 16; ++t) acc[t] = b;
  for (int c = 0; c < 300; ++c) {
    float wv = WihT[(size_t)c*1200 + g];
#pragma unroll
    for (int t = 0; t < 16; ++t) acc[t] += wv * xs[t][c];
  }
#pragma unroll
  for (int t = 0; t < 16; ++t) Xg[(size_t)(p0+t)*1200 + g] = acc[t];
}

// ---------------- BiLSTM recurrence; hybrid LDS+register weights (no spill) ----------------
// lane L (<600) owns gate g=(L&3)*150+(L>>2). Weights: j<64 in swizzled LDS, j>=64 in regs.
__global__ __launch_bounds__(640) void k_rec(
    const float* __restrict__ Xg, const float* __restrict__ WhhL,   // eWhh + (1+layer)*180000
    float* __restrict__ ys, float* __restrict__ fh, float* __restrict__ fc)
{
  const int dir = blockIdx.x, tid = threadIdx.x;
  __shared__ __align__(16) float wlo[600*64];          // 153.6 KB, XOR-swizzled rows of 256B
  __shared__ __align__(16) float hl[2][152];
  const int g = (tid & 3)*150 + (tid >> 2);
  const bool act = (tid < 600);
  // stage lower weights: element (gg,j) -> byte gg*256 + (((j>>2)<<4) ^ ((gg&7)<<4)) + (j&3)*4
  for (int i = tid; i < 600*64; i += 640) {
    int gg = i >> 6, j = i & 63;
    int fo = gg*64 + (((j >> 2) ^ (gg & 7)) << 2) + (j & 3);
    wlo[fo] = WhhL[(size_t)dir*90000 + (size_t)gg*150 + j];
  }
  // upper weights j=64..149 in registers (86 floats)
  float w_[86];
  if (act) {
    const float* wr = WhhL + (size_t)dir*90000 + (size_t)g*150 + 64;
#pragma unroll
    for (int m = 0; m < 86; ++m) w_[m] = wr[m];
  }
  if (tid < 152) { hl[0][tid] = 0.f; hl[1][tid] = 0.f; }
  float cr = 0.f;
  __syncthreads();
  int par = 0;
  const int gsw = g & 7;
  const float4* wb = (const float4*)(wlo + g*64);
  float xg = act ? Xg[(size_t)(dir ? INLEN-1 : 0)*1200 + dir*600 + g] : 0.f;
  for (int s = 0; s < INLEN; ++s) {
    const int pos = dir ? (INLEN-1-s) : s;
    const int nxt = dir ? (INLEN-2-s) : (s+1);
    float xg_nx = (s+1 < INLEN && act) ? Xg[(size_t)nxt*1200 + dir*600 + g] : 0.f;
    float acc = 0.f;
    if (act) {
      float aa[8];
#pragma unroll
      for (int q = 0; q < 8; ++q) aa[q] = 0.f;
      const float4* h4 = (const float4*)hl[par];
#pragma unroll
      for (int c4 = 0; c4 < 16; ++c4) {                  // j = 0..63 from LDS
        float4 h = h4[c4];
        float4 wv = wb[c4 ^ gsw];
        aa[c4&7] += wv.x*h.x + wv.y*h.y + wv.z*h.z + wv.w*h.w;
      }
#pragma unroll
      for (int j4 = 16; j4 < 37; ++j4) {                 // j = 64..147 from regs
        float4 h = h4[j4];
        int m = (j4-16)*4;
        aa[j4&7] += w_[m]*h.x + w_[m+1]*h.y + w_[m+2]*h.z + w_[m+3]*h.w;
      }
      acc = xg + ((aa[0]+aa[1])+(aa[2]+aa[3])) + ((aa[4]+aa[5])+(aa[6]+aa[7]))
            + w_[84]*hl[par][148] + w_[85]*hl[par][149];
    }
    float a1 = __shfl_xor(acc, 1);
    float a2 = __shfl_xor(acc, 2);
    float a3 = __shfl_xor(acc, 3);
    if (act && (tid & 3) == 0) {
      int d = tid >> 2;
      float cn = sigf(a1)*cr + sigf(acc)*tanhf_(a2);
      cr = cn;
      float hn = sigf(a3)*tanhf_(cn);
      hl[par^1][d] = hn;
      ys[(size_t)pos*300 + dir*150 + d] = hn;
    }
    __syncthreads();
    par ^= 1;
    xg = xg_nx;
  }
  if (act && (tid & 3) == 0) {
    int d = tid >> 2;
    fh[dir*150 + d] = hl[par][d];
    fc[dir*150 + d] = cr;
  }
}

// ---------------- schema update + history append (fused; 64 WGs) ----------------
__global__ void k_schema_upd(const float* __restrict__ SEi, const float* __restrict__ ys2,
                             float* __restrict__ SEo,
                             const float* __restrict__ fh, const float* __restrict__ fc,
                             float* __restrict__ HH, float* __restrict__ CH,
                             float* __restrict__ XH, int turn)
{
  const int row = blockIdx.x, tid = threadIdx.x;
  __shared__ float sl[300], al[128], red[4];
  for (int d = tid; d < 300; d += 256) sl[d] = SEi[(size_t)row*300 + d];
  __syncthreads();
  if (tid < 128) {
    float a = 0;
    const float* yr = ys2 + (size_t)tid*300;
    for (int d = 0; d < 300; ++d) a += sl[d]*yr[d];
    al[tid] = a;
  }
  __syncthreads();
  if (tid < 64) { float m = fmaxf(al[tid], al[tid+64]); m = wmax(m); if (tid==0) red[0]=m; }
  __syncthreads();
  if (tid < 128) al[tid] = __expf(al[tid] - red[0]);
  __syncthreads();
  if (tid < 64) { float s = al[tid] + al[tid+64]; s = wsum(s); if (tid==0) red[1]=s; }
  __syncthreads();
  const float invz = 1.0f/red[1];
  for (int d = tid; d < 300; d += 256) {
    float a = sl[d];
    for (int j = 0; j < 128; ++j) a += (al[j]*invz) * ys2[(size_t)j*300 + d];
    SEo[(size_t)row*300 + d] = a;
  }
  if (turn < MAXK) {
    for (int i = row*600 + tid; i < row*600 + 600; i += 256)
      XH[(size_t)turn*INLEN*300 + i] = ys2[i];
    if (row == 0)
      for (int d = tid; d < 300; d += 256) { HH[turn*300+d] = fh[d]; CH[turn*300+d] = fc[d]; }
  }
}

// ---------------- key family helper ----------------
__device__ __forceinline__ const float* key_ptr(int j, int nin, const float* SE1,
                                                const float* XH, const float* OH, int* fam)
{
  if (j < 64) { *fam = 0; return SE1 + (size_t)j*300; }
  if (j < 64+nin) { *fam = 1; return XH + (size_t)(j-64)*300; }
  *fam = 2; return OH + (size_t)(j-64-nin)*300;
}

// ---------------- per-turn tables, tiled: kw | g2k | ew | g1kT (normal loads) ---------------
__global__ __launch_bounds__(256) void k_tables(
    const float* __restrict__ SE1, const float* __restrict__ XH,
    const float* __restrict__ OH, const float* __restrict__ Wk,
    const float* __restrict__ Wih0T, const float* __restrict__ b0,
    const float* __restrict__ tWT, const float* __restrict__ qemb,
    const int* __restrict__ gt,
    float* __restrict__ KW, float* __restrict__ G2K,
    float* __restrict__ Ew, float* __restrict__ G1KT,
    int nin, int nout)
{
  const int NK = 64 + nin + nout;
  const int NT32 = NK >> 5;
  const int tid = threadIdx.x;
  const int b = blockIdx.x;
  __shared__ float A[32][301];
  const int wv4 = tid >> 6, ln = tid & 63;

  if (b < 2*NT32) {
    const int j0 = (b < NT32 ? b : b - NT32) * 32;
    int fam; const float* base = key_ptr(j0, nin, SE1, XH, OH, &fam);
    for (int jj = wv4*8; jj < wv4*8+8; ++jj)
      for (int c = ln; c < 300; c += 64)
        A[jj][c] = base[(size_t)jj*300 + c];
    __syncthreads();
    if (b < NT32) {
      const float* W = Wk + (size_t)(1+fam)*90000;
      for (int rep = 0; rep < 2; ++rep) {
        int c = tid + rep*256;
        if (c < 300) {
          float acc[32];
#pragma unroll
          for (int j = 0; j < 32; ++j) acc[j] = 0.f;
          for (int d = 0; d < 300; ++d) {
            float wvv = W[(size_t)d*300 + c];
#pragma unroll
            for (int j = 0; j < 32; ++j) acc[j] += A[j][d]*wvv;
          }
#pragma unroll
          for (int j = 0; j < 32; ++j) KW[(size_t)(j0+j)*300 + c] = acc[j];
        }
      }
    } else {
      const int cb = 300 + fam*300;
      for (int rep = 0; rep < 2; ++rep) {
        int r = tid + rep*256;
        if (r < 300) {
          float acc[32];
#pragma unroll
          for (int j = 0; j < 32; ++j) acc[j] = 0.f;
          for (int d = 0; d < 300; ++d) {
            float wvv = tWT[(size_t)(cb+d)*300 + r];
#pragma unroll
            for (int j = 0; j < 32; ++j) acc[j] += A[j][d]*wvv;
          }
#pragma unroll
          for (int j = 0; j < 32; ++j) G2K[(size_t)(j0+j)*300 + r] = acc[j];
        }
      }
    }
  } else if (b < 2*NT32 + 20) {
    const int idx = b - 2*NT32;
    const int gx = idx % 5, ty = idx / 5;
    const int g = gx*256 + tid;
    const int tb = ty*16;
    for (int i = tid; i < 16*300; i += 256) {
      int k = i / 300, c = i - k*300;
      int t = tb + k;
      int tok = (t < 63) ? gt[t] : 0;
      const float* e = (tok < VQ) ? qemb + (size_t)tok*300 : SE1 + (size_t)(tok-VQ)*300;
      A[k][c] = e[c];
    }
    __syncthreads();
    if (g < 1200) {
      float bb = b0[g];
      float acc[16];
#pragma unroll
      for (int k = 0; k < 16; ++k) acc[k] = bb;
      for (int c = 0; c < 300; ++c) {
        float wvv = Wih0T[(size_t)c*1200 + g];
#pragma unroll
        for (int k = 0; k < 16; ++k) acc[k] += wvv * A[k][c];
      }
#pragma unroll
      for (int k = 0; k < 16; ++k)
        if (tb + k < 63) Ew[(size_t)(tb+k)*1200 + g] = acc[k];
    }
  } else {
    const int idx = b - (2*NT32 + 20);
    const int j0 = (idx % NT32)*32, r0 = (idx / NT32)*64;
    int fam; const float* base = key_ptr(j0, nin, SE1, XH, OH, &fam);
    for (int jj = wv4*8; jj < wv4*8+8; ++jj)
      for (int c = ln; c < 300; c += 64)
        A[jj][c] = base[(size_t)jj*300 + c];
    __syncthreads();
    const int r = r0 + (tid & 63);
    const int jg = (tid >> 6)*8;
    const int cb = 300 + fam*300;
    float acc[8] = {0,0,0,0,0,0,0,0};
    if (r < 1200) {
      for (int c = 0; c < 300; ++c) {
        float wvv = Wih0T[(size_t)(cb+c)*1200 + r];
#pragma unroll
        for (int i = 0; i < 8; ++i) acc[i] += A[jg+i][c] * wvv;
      }
#pragma unroll
      for (int i = 0; i < 8; ++i) G1KT[(size_t)r*NK + j0 + jg + i] = acc[i];
    }
  }
}

// ---------------- persistent decoder ----------------
__global__ __launch_bounds__(256, 1) void k_dec(
    const float* __restrict__ KW, const float* __restrict__ G1KT,
    const float* __restrict__ Ew, const float* __restrict__ WqT,
    const float* __restrict__ av, const float* __restrict__ Wq0,
    const float* __restrict__ Wk0,
    const float* __restrict__ Whh0, const float* __restrict__ Wih1,
    const float* __restrict__ Whh1, const float* __restrict__ b1,
    const float* __restrict__ fh, const float* __restrict__ fc,
    const float* __restrict__ HH, const float* __restrict__ CH,
    float* __restrict__ h0b, float* __restrict__ c0b,
    float* __restrict__ xQW, float* __restrict__ xSC,
    float* __restrict__ xH1, float* __restrict__ xH2,
    float* __restrict__ Alog, float* __restrict__ H2log,
    int nin, int nout, int turn, int* __restrict__ flags)
{
  const int NK = 64 + nin + nout;
  const int w = blockIdx.x, tid = threadIdx.x;
  const int wv = tid >> 6, ln = tid & 63;
  const int grp = w & (NGRP-1);
  __shared__ float g1kl[20][1024];
  __shared__ float kwl[18][320];
  __shared__ float qWlp[3][320];
  __shared__ float vllp[3][320];
  __shared__ float ewl[63][20];
  __shared__ float scl[1024];
  __shared__ float dhl[320], h1l[320];
  __shared__ float pre1[20], pre2[20], zl[20], c1l[5], c2l[5];
  __shared__ float redA[4], alscA[8];
  __shared__ float wr0[4], wr1[4], wr2[4], rm[3], rz[3];
  const float SENTF = __uint_as_float(SENTU);

  for (int i = w*256 + tid; i < NGRP*GQW; i += NWD*256) gstore(xQW + i, SENTF);
  for (int i = w*256 + tid; i < NGRP*GSC; i += NWD*256) gstore(xSC + i, SENTF);
  for (int i = w*256 + tid; i < NGRP*GH;  i += NWD*256) gstore(xH1 + i, SENTF);
  for (int i = w*256 + tid; i < NGRP*GH;  i += NWD*256) gstore(xH2 + i, SENTF);

  for (int i = tid; i < 20*1024; i += 256) {
    int o = i >> 10, j = i & 1023;
    int row = w*5 + (o % 5) + 300*(o / 5);
    g1kl[o][j] = (j < NK) ? G1KT[(size_t)row*NK + j] : 0.f;
  }
  for (int i = tid; i < 18*320; i += 256) {
    int jo = i / 320, c = i - jo*320;
    int j = w*18 + jo;
    kwl[jo][c] = (c < 300 && j < NK) ? KW[(size_t)j*300 + c] : 0.f;
  }
  for (int i = tid; i < 3*320; i += 256) {
    int f = i / 320, c = i - f*320;
    vllp[f][c] = (c < 300) ? av[300 + f*300 + c] : 0.f;
    qWlp[f][c] = 0.f;
  }
  for (int i = tid; i < 63*20; i += 256) {
    int t = i / 20, o = i - t*20;
    int row = w*5 + (o % 5) + 300*(o / 5);
    ewl[t][o] = Ew[(size_t)t*1200 + row];
  }
  if (tid < 20) { dhl[300+tid] = 0.f; h1l[300+tid] = 0.f; }

  float rwh0[5][5], rwh1[5][5], rwi1[5][5], rwq4[4][5], b1r[5];
#pragma unroll
  for (int r = 0; r < 5; ++r) {
    int row = w*5 + r + 300*wv;
    b1r[r] = b1[row];
#pragma unroll
    for (int k = 0; k < 5; ++k) {
      int d = ln + 64*k;
      rwh0[r][k] = (d < 300) ? Whh0[(size_t)row*300 + d] : 0.f;
      rwh1[r][k] = (d < 300) ? Whh1[(size_t)row*300 + d] : 0.f;
      rwi1[r][k] = (d < 300) ? Wih1[(size_t)row*300 + d] : 0.f;
    }
  }
#pragma unroll
  for (int r = 0; r < 4; ++r) {
    int o = r*4 + wv;
    int q = w*15 + ((o < 15) ? o : 0);
    int fam = q / 300, c = q - fam*300;
    const float* bp = WqT + ((size_t)(1+fam)*300 + c)*300;
#pragma unroll
    for (int k = 0; k < 5; ++k) {
      int d = ln + 64*k;
      rwq4[r][k] = (o < 15 && d < 300) ? bp[d] : 0.f;
    }
  }
  const int jlo = (w*18 < NK) ? w*18 : NK-1;
  const int jhi = (w*18+17 < NK) ? w*18+17 : NK-1;
  const int f0 = (jlo < 64) ? 0 : (jlo < 64+nin ? 1 : 2);
  const int f1 = (jhi < 64) ? 0 : (jhi < 64+nin ? 1 : 2);
  __syncthreads();

  if (w == 0) {
    if (turn == 0) {
      for (int d = tid; d < 300; d += 256) { gstore(h0b+d, fh[d]); gstore(c0b+d, fc[d]); }
    } else {
      const int nh = turn;
      for (int d = tid; d < 300; d += 256) dhl[d] = fh[d];
      __syncthreads();
      for (int rep = 0; rep < 2; ++rep) {
        const float* keys = rep ? CH : HH;
        for (int c = tid; c < 300; c += 256) {
          float a = 0;
          for (int d = 0; d < 300; ++d) a += dhl[d]*Wq0[(size_t)d*300 + c];
          h1l[c] = a;
        }
        __syncthreads();
        for (int k = 0; k < nh; ++k) {
          const float* Kr = keys + (size_t)k*300;
          float part = 0;
          for (int c = tid; c < 300; c += 256) {
            float kw = 0;
            for (int d = 0; d < 300; ++d) kw += Kr[d]*Wk0[(size_t)d*300 + c];
            part += av[c]*tanhf_(h1l[c] + kw);
          }
          part = wsum(part);
          if (ln == 0) redA[wv] = part;
          __syncthreads();
          if (tid == 0) alscA[k] = redA[0]+redA[1]+redA[2]+redA[3];
          __syncthreads();
        }
        if (tid == 0) {
          float m = -1e30f;
          for (int k = 0; k < nh; ++k) m = fmaxf(m, alscA[k]);
          float z = 0;
          for (int k = 0; k < nh; ++k) { alscA[k] = __expf(alscA[k]-m); z += alscA[k]; }
          for (int k = 0; k < nh; ++k) alscA[k] /= z;
        }
        __syncthreads();
        if (rep == 0) {
          for (int c = tid; c < 300; c += 256) {
            float a = dhl[c];
            for (int k = 0; k < nh; ++k) a += alscA[k]*keys[(size_t)k*300 + c];
            scl[c] = a; gstore(h0b+c, a);
          }
          __syncthreads();
          for (int d = tid; d < 300; d += 256) dhl[d] = fc[d];
          __syncthreads();
        } else {
          for (int c = tid; c < 300; c += 256) {
            float a = scl[c];
            for (int k = 0; k < nh; ++k) a += alscA[k]*keys[(size_t)k*300 + c];
            gstore(c0b+c, a);
          }
        }
      }
    }
  }
  garrive(flags, w, turn+1);
  gwait(flags, turn+1);

  for (int i = tid; i < 300; i += 256) { float v = gload(h0b+i); dhl[i] = v; h1l[i] = v; }
  if (tid < 5) { float v = gload(c0b + w*5 + tid); c1l[tid] = v; c2l[tid] = v; }
  __syncthreads();

  for (int t = 0; t < TSTEPS; ++t) {
    if (t) pollfetch<2>(xH2 + (size_t)grp*GH + (size_t)(t-1)*320, dhl, 300, 0, tid);
#pragma unroll
    for (int r = 0; r < 4; ++r) {
      float a = 0;
#pragma unroll
      for (int k = 0; k < 5; ++k) a += rwq4[r][k]*dhl[ln + 64*k];
      a = wsum(a);
      int o = r*4 + wv;
      if (ln < NGRP && o < 15) {
        int q = w*15 + o, fam = q/300, c = q - fam*300;
        gpub(xQW + (size_t)ln*GQW + (size_t)t*960 + fam*320 + c, a);
      }
    }
#pragma unroll
    for (int r = 0; r < 5; ++r) {
      float a1 = 0, a2 = 0;
#pragma unroll
      for (int k = 0; k < 5; ++k) {
        float hv = h1l[ln + 64*k], dv = dhl[ln + 64*k];
        a1 += rwh0[r][k]*hv; a2 += rwh1[r][k]*dv;
      }
      a1 = wsum(a1); a2 = wsum(a2);
      if (ln == 0) { pre1[wv*5+r] = a1; pre2[wv*5+r] = a2 + b1r[r]; }
    }

    pollfetch<3>(xQW + (size_t)grp*GQW + (size_t)t*960 + f0*320, &qWlp[f0][0], (f1-f0+1)*320, 320, tid);
#pragma unroll
    for (int r = 0; r < 5; ++r) {
      int jo = wv*5 + r;
      int j = w*18 + jo;
      bool va = (jo < 18) && (j < NK);
      int f = va ? ((j < 64) ? 0 : (j < 64+nin ? 1 : 2)) : 0;
      int jc = (jo < 18) ? jo : 0;
      float a = 0;
#pragma unroll
      for (int k = 0; k < 5; ++k) {
        int c = ln + 64*k;
        a += vllp[f][c] * tanhf_(qWlp[f][c] + kwl[jc][c]);
      }
      a = wsum(a);
      if (ln < NGRP && va) gpub(xSC + (size_t)ln*GSC + (size_t)t*1024 + j, a);
    }

    pollfetch<4>(xSC + (size_t)grp*GSC + (size_t)t*1024, scl, NK, 0, tid);
    {
      float m0=-1e30f, m1=-1e30f, m2=-1e30f;
      for (int j = tid; j < NK; j += 256) {
        float x = scl[j];
        if (j < 64) m0 = fmaxf(m0,x); else if (j < 64+nin) m1 = fmaxf(m1,x); else m2 = fmaxf(m2,x);
      }
      m0 = wmax(m0); m1 = wmax(m1); m2 = wmax(m2);
      if (ln==0){ wr0[wv]=m0; wr1[wv]=m1; wr2[wv]=m2; }
      __syncthreads();
      if (tid==0){
        rm[0]=fmaxf(fmaxf(wr0[0],wr0[1]),fmaxf(wr0[2],wr0[3]));
        rm[1]=fmaxf(fmaxf(wr1[0],wr1[1]),fmaxf(wr1[2],wr1[3]));
        rm[2]=fmaxf(fmaxf(wr2[0],wr2[1]),fmaxf(wr2[2],wr2[3]));
      }
      __syncthreads();
      float s0=0,s1=0,s2=0;
      for (int j = tid; j < NK; j += 256) {
        int f = (j<64)?0:(j<64+nin?1:2);
        float e = __expf(scl[j] - rm[f]);
        scl[j] = e;
        if (f==0) s0+=e; else if (f==1) s1+=e; else s2+=e;
      }
      s0=wsum(s0); s1=wsum(s1); s2=wsum(s2);
      if (ln==0){ wr0[wv]=s0; wr1[wv]=s1; wr2[wv]=s2; }
      __syncthreads();
      if (tid==0){
        rz[0]=wr0[0]+wr0[1]+wr0[2]+wr0[3];
        rz[1]=wr1[0]+wr1[1]+wr1[2]+wr1[3];
        rz[2]=wr2[0]+wr2[1]+wr2[2]+wr2[3];
      }
      __syncthreads();
    }
    const int KC = NK >> 6;
    const int c1e = 1 + (nin >> 6);
    float inv0 = 1.0f/rz[0], inv1 = 1.0f/rz[1];
    float inv2 = (KC > c1e) ? 1.0f/rz[2] : 0.f;
    {
#pragma unroll 1
      for (int r = 0; r < 5; ++r) {
        int o = wv*5 + r;
        float a0 = scl[ln]*g1kl[o][ln];
        float a1 = 0, a2 = 0;
        for (int k = 1; k < c1e; ++k) { int j = ln + 64*k; a1 += scl[j]*g1kl[o][j]; }
        for (int k = c1e; k < KC; ++k) { int j = ln + 64*k; a2 += scl[j]*g1kl[o][j]; }
        float a = a0*inv0 + a1*inv1 + a2*inv2;
        a = wsum(a);
        if (ln == 0) zl[o] = a + ewl[t][o] + pre1[o];
      }
    }
    __syncthreads();
    if (tid < 5) {
      float ii=zl[tid], ff=zl[5+tid], gg=zl[10+tid], oo=zl[15+tid];
      float cn = sigf(ff)*c1l[tid] + sigf(ii)*tanhf_(gg);
      c1l[tid] = cn;
      float h1v = sigf(oo)*tanhf_(cn);
#pragma unroll
      for (int g = 0; g < NGRP; ++g)
        gpub(xH1 + (size_t)g*GH + (size_t)t*320 + w*5 + tid, h1v);
    }
    if (tid < 18) {
      int j = w*18 + tid;
      if (j < NK) {
        int f = (j<64)?0:(j<64+nin?1:2);
        float iv = (f==0)?inv0:((f==1)?inv1:inv2);
        Alog[(size_t)t*1024 + j] = scl[j]*iv;
      }
    }

    pollfetch<2>(xH1 + (size_t)grp*GH + (size_t)t*320, h1l, 300, 0, tid);
#pragma unroll
    for (int r = 0; r < 5; ++r) {
      float a = 0;
#pragma unroll
      for (int k = 0; k < 5; ++k) a += rwi1[r][k]*h1l[ln + 64*k];
      a = wsum(a);
      if (ln == 0) zl[wv*5+r] = a + pre2[wv*5+r];
    }
    __syncthreads();
    if (tid < 5) {
      int d = w*5 + tid;
      float ii=zl[tid], ff=zl[5+tid], gg=zl[10+tid], oo=zl[15+tid];
      float cn = sigf(ff)*c2l[tid] + sigf(ii)*tanhf_(gg);
      c2l[tid] = cn;
      float hn = sigf(oo)*tanhf_(cn);
#pragma unroll
      for (int g = 0; g < NGRP; ++g)
        gpub(xH2 + (size_t)g*GH + (size_t)t*320 + d, hn);
      H2log[(size_t)t*300 + d] = hn;
    }
  }
}

// ---------------- fused: o63 = tanh(H2@T.T + A@G2K); t63 = o63@colW.T ----------------
__global__ void k_ctxout2(const float* __restrict__ H2, const float* __restrict__ Al,
                          const float* __restrict__ G2K, const float* __restrict__ tWT,
                          const float* __restrict__ colW,
                          float* __restrict__ o63, float* __restrict__ t63, int NK)
{
  const int t = blockIdx.x, tid = threadIdx.x;
  __shared__ float ol[304], h2l[304], all[1024];
  for (int d = tid; d < 300; d += 256) h2l[d] = H2[(size_t)t*300 + d];
  for (int j = tid; j < NK; j += 256) all[j] = Al[(size_t)t*1024 + j];
  __syncthreads();
  for (int r = tid; r < 300; r += 256) {
    float a = 0;
    for (int d = 0; d < 300; ++d) a += h2l[d]*tWT[(size_t)d*300 + r];
    for (int j = 0; j < NK; ++j) a += all[j]*G2K[(size_t)j*300 + r];
    float v = tanhf_(a);
    ol[r] = v;
    o63[(size_t)t*300 + r] = v;
  }
  __syncthreads();
  for (int e = tid; e < 300; e += 256) {
    float a = 0;
    const float* wc = colW + (size_t)e*300;
    for (int d = 0; d < 300; ++d) a += ol[d]*wc[d];
    t63[(size_t)t*300 + e] = a;
  }
}

// ---------------- vocab + schema scores: single pass, LDS-staged o63 ----------------
__global__ __launch_bounds__(256) void k_score(
    const float* __restrict__ o63, const float* __restrict__ t63,
    const float* __restrict__ sqlW, const float* __restrict__ sqlb,
    const float* __restrict__ SE1, float* __restrict__ Dout)
{
  const int vb = blockIdx.x, tid = threadIdx.x;
  const int v = vb*256 + tid;
  if ((vb+1)*256 <= VQ) {
    __shared__ __align__(16) float olT[300][68];
    for (int i = tid; i < 63*300; i += 256) {
      int k = i / 300, d = i - k*300;
      olT[d][k] = o63[i];
    }
    for (int d = tid; d < 300; d += 256) olT[d][63] = 0.f;
    __syncthreads();
    const float4* w4 = (const float4*)(sqlW + (size_t)v*300);
    float acc[64];
#pragma unroll
    for (int k = 0; k < 64; ++k) acc[k] = 0.f;
    for (int d4 = 0; d4 < 75; ++d4) {
      float4 wq = w4[d4];
      float wa[4] = {wq.x, wq.y, wq.z, wq.w};
#pragma unroll
      for (int s = 0; s < 4; ++s) {
        float ws = wa[s];
        const float4* row = (const float4*)&olT[d4*4+s][0];
#pragma unroll
        for (int k4 = 0; k4 < 16; ++k4) {
          float4 ov = row[k4];
          acc[4*k4+0] += ws*ov.x; acc[4*k4+1] += ws*ov.y;
          acc[4*k4+2] += ws*ov.z; acc[4*k4+3] += ws*ov.w;
        }
      }
    }
    const float b = sqlb[v];
    for (int k = 0; k < 63; ++k) Dout[(size_t)k*VOUT + v] = acc[k] + b;
  } else {
    if (v >= VOUT) return;
    const bool isv = (v < VQ);
    const float* w = isv ? sqlW + (size_t)v*300 : SE1 + (size_t)(v - VQ)*300;
    const float* src = isv ? o63 : t63;
    float acc[63];
#pragma unroll
    for (int k = 0; k < 63; ++k) acc[k] = 0.f;
    for (int d = 0; d < 300; ++d) {
      float wv_ = w[d];
      for (int k = 0; k < 63; ++k) acc[k] += wv_ * src[(size_t)k*300 + d];
    }
    const float b = isv ? sqlb[v] : 0.f;
    for (int k = 0; k < 63; ++k) Dout[(size_t)k*VOUT + v] = acc[k] + b;
  }
}

// ---------------- log-softmax + argmax + OH row write ----------------
__global__ void k_lsm(float* __restrict__ rows, const float* __restrict__ qemb,
                      const float* __restrict__ SE1, float* __restrict__ OHt)
{
  const int t = blockIdx.x, tid = threadIdx.x, wv = tid>>6, ln = tid&63;
  float* row = rows + (size_t)t*VOUT;
  __shared__ float rv[4], rs[4];
  __shared__ int ri[4];
  float m = -1e30f; int mi = VOUT;
  for (int j = tid; j < VOUT; j += 256) {
    float x = row[j];
    if (x > m) { m = x; mi = j; }
  }
#pragma unroll
  for (int o = 32; o; o >>= 1) {
    float om = __shfl_xor(m, o); int oi = __shfl_xor(mi, o);
    if (om > m || (om == m && oi < mi)) { m = om; mi = oi; }
  }
  if (ln == 0) { rv[wv] = m; ri[wv] = mi; }
  __syncthreads();
  if (tid == 0) {
    for (int k = 1; k < 4; ++k)
      if (rv[k] > rv[0] || (rv[k] == rv[0] && ri[k] < ri[0])) { rv[0]=rv[k]; ri[0]=ri[k]; }
  }
  __syncthreads();
  const float M = rv[0];
  float s = 0;
  for (int j = tid; j < VOUT; j += 256) s += __expf(row[j] - M);
  s = wsum(s);
  if (ln == 0) rs[wv] = s;
  __syncthreads();
  const float L = M + logf(rs[0]+rs[1]+rs[2]+rs[3]);
  for (int j = tid; j < VOUT; j += 256) row[j] -= L;
  if (OHt) {
    int id = ri[0];
    const float* src = (id < VQ) ? qemb + (size_t)id*300 : SE1 + (size_t)(id-VQ)*300;
    for (int d = tid; d < 300; d += 256) {
      OHt[(size_t)(t+1)*300 + d] = src[d];
      if (t == 0) OHt[d] = qemb[d];
    }
  }
}

extern "C" void kernel_launch(void* const* d_in, const int* in_sizes, int n_in,
                              void* d_out, int out_size, void* d_ws, size_t ws_size,
                              hipStream_t stream)
{
  const float* utter = (const float*)d_in[0];
  const float* qemb  = (const float*)d_in[1];
  const float* temb  = (const float*)d_in[2];
  const float* eWih  = (const float*)d_in[3];
  const float* eWhh  = (const float*)d_in[4];
  const float* eb    = (const float*)d_in[5];
  const float* aWq   = (const float*)d_in[6];
  const float* aWk   = (const float*)d_in[7];
  const float* av    = (const float*)d_in[8];
  const float* dWih0 = (const float*)d_in[9];
  const float* dWhh0 = (const float*)d_in[10];
  const float* db0   = (const float*)d_in[11];
  const float* dWih1 = (const float*)d_in[12];
  const float* dWhh1 = (const float*)d_in[13];
  const float* db1   = (const float*)d_in[14];
  const float* tW    = (const float*)d_in[15];
  const float* sqlW  = (const float*)d_in[16];
  const float* sqlb  = (const float*)d_in[17];
  const float* colW  = (const float*)d_in[18];
  const int* stok    = (const int*)d_in[19];
  const int* iseq    = (const int*)d_in[20];
  const int* ogt     = (const int*)d_in[21];
  float* dout = (float*)d_out;

  float* base = (float*)d_ws;
  size_t off = 0;
  auto A = [&](size_t n)->float*{ float* r = base + off; off += (n + 63) & ~(size_t)63; return r; };
  float* SE    = A(7*64*300);
  float* XH    = A(5*128*300);
  float* OH    = A(5*64*300);
  float* HH    = A(5*300);
  float* CH    = A(5*300);
  float* ys1   = A(128*300);
  float* ys2   = A(128*300);
  float* Xg    = A(128*1200);
  float* fh    = A(320);
  float* fc    = A(320);
  float* fhs   = A(320);
  float* fcs   = A(320);
  float* h0b   = A(320);
  float* c0b   = A(320);
  float* xQW   = A(NGRP*GQW);
  float* xSC   = A(NGRP*GSC);
  float* xH1   = A(NGRP*GH);
  float* xH2   = A(NGRP*GH);
  float* KW    = A(1024*300);
  float* G1KT  = A(1200*1024);
  float* G2K   = A(1024*300);
  float* EwB   = A(63*1200);
  float* Alog  = A(63*1024);
  float* H2lg  = A(64*300);
  float* o63   = A(64*300);
  float* t63   = A(64*300);
  A(512);
  float* WqT   = A(4*300*300);
  float* Wih0T = A(1200*1200);
  float* tWT   = A(1200*300);
  float* eWT   = A(2*300*1200);
  int* dflags = (int*)A(NWD*FPAD);
  (void)ws_size; (void)in_sizes; (void)n_in; (void)out_size;

  k_setup<<<240, 256, 0, stream>>>(aWq, WqT, dWih0, Wih0T, tW, tWT, eWih, eWT, eWhh,
                                   temb, stok, eb, SE, dflags);

  for (int i = 0; i < NTURNS; ++i) {
    const int kin  = (i+1 < MAXK) ? (i+1) : MAXK;
    const int kout = (i < MAXK) ? i : MAXK;
    const int nin = kin*128, nout = kout*64;
    const int NK = 64 + nin + nout;
    const int NT32 = NK/32;
    float* SEi = SE + (size_t)i*19200;
    float* SEo = SE + (size_t)(i+1)*19200;

    k_gemm_xe<<<dim3(5,8), 256, 0, stream>>>(utter, SEi, iseq + i*INLEN, 0,
                                             eWT, eb + 1200, Xg);
    k_rec<<<2, 640, 0, stream>>>(Xg, eWhh + 180000, ys1, fhs, fcs);
    k_gemm_xe<<<dim3(5,8), 256, 0, stream>>>(ys1, SEi, iseq + i*INLEN, 1,
                                             eWT + 360000, eb + 2400, Xg);
    k_rec<<<2, 640, 0, stream>>>(Xg, eWhh + 360000, ys2, fh, fc);
    k_schema_upd<<<64, 256, 0, stream>>>(SEi, ys2, SEo, fh, fc, HH, CH, XH, i);
    k_tables<<<2*NT32 + 20 + NT32*19, 256, 0, stream>>>(
        SEo, XH, OH, aWk, Wih0T, db0, tWT, qemb, ogt + i*64,
        KW, G2K, EwB, G1KT, nin, nout);
    k_dec<<<NWD, 256, 0, stream>>>(KW, G1KT, EwB, WqT, av, aWq, aWk,
                                   dWhh0, dWih1, dWhh1, db1, fh, fc, HH, CH,
                                   h0b, c0b, xQW, xSC, xH1, xH2, Alog, H2lg,
                                   nin, nout, i, dflags);
    k_ctxout2<<<63, 256, 0, stream>>>(H2lg, Alog, G2K, tWT, colW, o63, t63, NK);
    k_score<<<118, 256, 0, stream>>>(o63, t63, sqlW, sqlb, SEo, dout + (size_t)i*63*VOUT);
    k_lsm<<<63, 256, 0, stream>>>(dout + (size_t)i*63*VOUT, qemb, SEo,
                                  (i < MAXK) ? OH + (size_t)i*19200 : nullptr);
  }
}